// Round 12
// baseline (226.886 us; speedup 1.0000x reference)
//
#include <hip/hip_runtime.h>
#include <hip/hip_bf16.h>
#include <math.h>

typedef __hip_bfloat16 bf16;
typedef __attribute__((ext_vector_type(8))) short short8;   // 8 bf16 = 4 VGPRs (MFMA A/B frag)
typedef __attribute__((ext_vector_type(4))) float f32x4;    // MFMA C/D frag

static constexpr int kB = 2;
static constexpr int kT = 2048;
static constexpr int kDIM = 1024;
static constexpr int kNMETA = 4;
static constexpr int kTEXT = kT + kNMETA;   // 2052
static constexpr int kMEXT = kB * kTEXT;    // 4104
static constexpr int kMPAD = 4224;          // 33*128
static constexpr int kMX = kB * kT;         // 4096
static constexpr int kQT = 33;
static constexpr int kTP = 2112;            // 33*64

// ---------- workspace layout (bytes); ws ~268 MB ----------
static constexpr size_t oXE = 0;                                  // x_ext bf16 [4224][1024]
static constexpr size_t oYB = 0;                                  // aliases XE (dead after GEMMs)
static constexpr size_t oLU = 8650752;                            // la/u interleaved f32x2 [4096][128]
static constexpr size_t oCC = oLU + (size_t)kMX * 128 * 8;        // Cc f32 [4096][128]
static constexpr size_t oHL = oCC + (size_t)kMX * 128 * 4;        // final h bf16 [4096][128]
static constexpr size_t oX0 = oHL + (size_t)kMX * 128 * 2;        // x0 f32 [4096][8]
static constexpr size_t oQP = oX0 + (size_t)kMX * 8 * 4;          // Qp bf16 [b][8][2112][64]
static constexpr size_t oKP = oQP + (size_t)kB * 8 * kTP * 64 * 2;// Kp bf16 [b][4][2112][64]
static constexpr size_t oVT = oKP + (size_t)kB * 4 * kTP * 64 * 2;// Vt bf16 [b][4][64][2112]
static constexpr size_t oWP = oVT + (size_t)kB * 4 * 64 * kTP * 2;// Wproj bf16 [1024][1024]
static constexpr size_t oWQ = oWP + (size_t)1024 * 1024 * 2;      // WQKV+WSX bf16 [1536][1024]
static constexpr size_t oAO = 134217728;                          // attn partial O f32 [2][b][8][2112][64]
static constexpr size_t oAL = oAO + (size_t)2 * kB * 8 * kTP * 64 * 4;  // partial l f32 [2][b][8][2112]

#define GLD_LDS16(gp, lp)                                                          \
  __builtin_amdgcn_global_load_lds((const __attribute__((address_space(1))) void*)(gp), \
                                   (__attribute__((address_space(3))) void*)(lp), 16, 0, 0)

__device__ __forceinline__ short bf2s(float f) {
  union { bf16 h; short s; } u;
  u.h = __float2bfloat16(f);
  return u.s;
}

__device__ __forceinline__ uint4 pack8(float4 a, float4 b) {
  union { bf16 h[8]; uint4 v; } u;
  u.h[0] = __float2bfloat16(a.x); u.h[1] = __float2bfloat16(a.y);
  u.h[2] = __float2bfloat16(a.z); u.h[3] = __float2bfloat16(a.w);
  u.h[4] = __float2bfloat16(b.x); u.h[5] = __float2bfloat16(b.y);
  u.h[6] = __float2bfloat16(b.z); u.h[7] = __float2bfloat16(b.w);
  return u.v;
}

// ---- prep: weight converts + x_ext build + QP/KP/VT tail zeroing, one launch ----
__global__ __launch_bounds__(256) void prep_all(const float* __restrict__ cq, const float* __restrict__ ck,
                                                const float* __restrict__ cv, const float* __restrict__ sw,
                                                const float* __restrict__ pw,
                                                const float* __restrict__ x, const float* __restrict__ meta,
                                                bf16* __restrict__ wqkvsx, bf16* __restrict__ wproj,
                                                bf16* __restrict__ xe,
                                                bf16* __restrict__ Qp, bf16* __restrict__ Kp,
                                                bf16* __restrict__ Vt) {
  int i = blockIdx.x * 256 + threadIdx.x;
  if (i < 327680) {                       // seg0: weights
    int row = i >> 7, v = i & 127;
    const float* src; bf16* dst;
    if (row < 512)       { src = cq + (size_t)row * 1024;          dst = wqkvsx + (size_t)row * 1024; }
    else if (row < 768)  { src = ck + (size_t)(row - 512) * 1024;  dst = wqkvsx + (size_t)row * 1024; }
    else if (row < 1024) { src = cv + (size_t)(row - 768) * 1024;  dst = wqkvsx + (size_t)row * 1024; }
    else if (row < 1536) { src = sw + (size_t)(row - 1024) * 1024; dst = wqkvsx + (size_t)row * 1024; }
    else                 { src = pw + (size_t)(row - 1536) * 1024; dst = wproj + (size_t)(row - 1536) * 1024; }
    float4 a0 = ((const float4*)src)[v * 2], a1 = ((const float4*)src)[v * 2 + 1];
    ((uint4*)dst)[v] = pack8(a0, a1);
  } else if (i < 868352) {                // seg1: x_ext
    int j = i - 327680;
    int r = j >> 7, v = j & 127;
    uint4 val = {0u, 0u, 0u, 0u};
    if (r < kMEXT) {
      int b = r / kTEXT, te = r - b * kTEXT;
      const float* src = (te < kNMETA) ? (meta + (size_t)te * kDIM)
                                       : (x + ((size_t)b * kT + (te - kNMETA)) * kDIM);
      float4 a0 = ((const float4*)src)[v * 2];
      float4 a1 = ((const float4*)src)[v * 2 + 1];
      val = pack8(a0, a1);
    }
    ((uint4*)(xe + (size_t)r * kDIM))[v] = val;
  } else {                                // seg2: zero pad tails (uint = 2 bf16)
    int j = i - 868352;
    if (j < 30720) {            // QP tails
      int k = j & 31, te = (j >> 5) % 60, bh = j / (60 * 32);
      *(unsigned int*)(Qp + ((size_t)bh * kTP + 2052 + te) * 64 + k * 2) = 0u;
    } else if (j < 46080) {     // KP tails
      int jj = j - 30720;
      int k = jj & 31, te = (jj >> 5) % 60, bh = jj / (60 * 32);
      *(unsigned int*)(Kp + ((size_t)bh * kTP + 2052 + te) * 64 + k * 2) = 0u;
    } else if (j < 61440) {     // VT tails
      int jj = j - 46080;
      int k = jj % 30, rowd = jj / 30;
      *(unsigned int*)(Vt + (size_t)rowd * kTP + 2052 + k * 2) = 0u;
    }
  }
}

// ========== 128x64-tile bf16 GEMM (K=1024, BK=32), global_load_lds staging ==========
// MODE 0: fused QKV+SSM-prep epilogue:
//   tiles 0-7: Q -> RMS+RoPE+gain -> QP ; 8-11: K -> RMS+RoPE -> KP ;
//   12-15: V -> transposed VT ; 16-23: X -> LDS -> MFMA vs [dtw;Bw;Cw] -> LU/CC/X0.
// MODE 2: proj (f32 out).
template <int MODE>
__global__ __launch_bounds__(256) void gemm_t(const bf16* __restrict__ A,
                                              const bf16* __restrict__ W,
                                              void* __restrict__ O0, void* __restrict__ O1,
                                              void* __restrict__ O2,
                                              const float* __restrict__ q_gain,
                                              const float* __restrict__ dtw, const float* __restrict__ dtb,
                                              const float* __restrict__ Bw, const float* __restrict__ Cw,
                                              const float* __restrict__ logA,
                                              float* __restrict__ LU, float* __restrict__ CC,
                                              float* __restrict__ X0) {
  constexpr int SMEM_SZ = (MODE == 0) ? 25344 : 12288;   // MODE0: X[128][72] + W48[48][72] overlay
  __shared__ char smem[SMEM_SZ];
  const int tid = threadIdx.x;
  const int wave = tid >> 6, lane = tid & 63;
  const int quad = lane >> 4, l16 = lane & 15;
  const int bm = blockIdx.y * 128, bn = blockIdx.x * 64;
  const int srow = tid >> 2, scol = (tid & 3) * 8;
  const bf16* ag0 = A + (size_t)(bm + srow) * 1024 + scol;
  const bf16* ag1 = A + (size_t)(bm + 64 + srow) * 1024 + scol;
  const bf16* bg0 = W + (size_t)(bn + srow) * 1024 + scol;
  char* asb = smem + wave * 1024;
  char* bsb = smem + 8192 + wave * 1024;
  f32x4 acc[2][4] = {};
  for (int k0 = 0; k0 < 1024; k0 += 32) {
    __syncthreads();
    GLD_LDS16(ag0, asb);
    GLD_LDS16(ag1, asb + 4096);
    GLD_LDS16(bg0, bsb);
    ag0 += 32; ag1 += 32; bg0 += 32;
    __syncthreads();
    short8 af[2], bfr[4];
#pragma unroll
    for (int mi = 0; mi < 2; ++mi)
      af[mi] = *(const short8*)(smem + (size_t)(wave * 32 + mi * 16 + l16) * 64 + quad * 16);
#pragma unroll
    for (int ni = 0; ni < 4; ++ni)
      bfr[ni] = *(const short8*)(smem + 8192 + (size_t)(ni * 16 + l16) * 64 + quad * 16);
#pragma unroll
    for (int mi = 0; mi < 2; ++mi)
#pragma unroll
      for (int ni = 0; ni < 4; ++ni)
        acc[mi][ni] = __builtin_amdgcn_mfma_f32_16x16x32_bf16(af[mi], bfr[ni], acc[mi][ni], 0, 0, 0);
  }
  // ---- epilogue ----
  if constexpr (MODE == 2) {
#pragma unroll
    for (int mi = 0; mi < 2; ++mi)
#pragma unroll
      for (int ni = 0; ni < 4; ++ni) {
        int colg = bn + ni * 16 + l16;
#pragma unroll
        for (int r = 0; r < 4; ++r) {
          int row = bm + wave * 32 + mi * 16 + quad * 4 + r;
          ((float*)O0)[(size_t)row * 1024 + colg] = acc[mi][ni][r];
        }
      }
  } else {
    const int tile = blockIdx.x;
    if (tile < 16) {
      float gain = (tile < 8) ? q_gain[tile] * 0.125f : 1.f;
      float inv0 = exp2f(-13.287712379549449f * (float)l16 * (1.f / 32.f));
      float inv1 = exp2f(-13.287712379549449f * (float)(l16 + 16) * (1.f / 32.f));
#pragma unroll
      for (int mi = 0; mi < 2; ++mi) {
        int row0 = bm + wave * 32 + mi * 16 + quad * 4;
        if (row0 >= kMEXT) continue;          // 4-row group fully pad
        int b = row0 >= kTEXT ? 1 : 0;
        int te0 = row0 - b * kTEXT;
        if (tile < 12) {
          float ss[4];
#pragma unroll
          for (int r = 0; r < 4; ++r) {
            float s = 0.f;
#pragma unroll
            for (int ni = 0; ni < 4; ++ni) s += acc[mi][ni][r] * acc[mi][ni][r];
#pragma unroll
            for (int off = 1; off < 16; off <<= 1) s += __shfl_xor(s, off, 64);
            ss[r] = s;
          }
          bf16* base = (tile < 8)
            ? (bf16*)O0 + (((size_t)(b * 8 + tile)) * kTP + te0) * 64 + l16
            : (bf16*)O1 + (((size_t)(b * 4 + tile - 8)) * kTP + te0) * 64 + l16;
#pragma unroll
          for (int r = 0; r < 4; ++r) {
            float rn = rsqrtf(ss[r] * (1.f / 64.f) + 1e-6f) * gain;
            float te = (float)(te0 + r);
            float a0 = te * inv0, a1 = te * inv1;
            float c0 = __cosf(a0), s0 = __sinf(a0);
            float c1 = __cosf(a1), s1 = __sinf(a1);
            float v0 = acc[mi][0][r] * rn, v1 = acc[mi][1][r] * rn;
            float v2 = acc[mi][2][r] * rn, v3 = acc[mi][3][r] * rn;
            bf16* dst = base + (size_t)r * 64;
            dst[0]  = __float2bfloat16(v0 * c0 - v2 * s0);
            dst[16] = __float2bfloat16(v1 * c1 - v3 * s1);
            dst[32] = __float2bfloat16(v0 * s0 + v2 * c0);
            dst[48] = __float2bfloat16(v1 * s1 + v3 * c1);
          }
        } else {
          int hv = tile - 12;
#pragma unroll
          for (int ni = 0; ni < 4; ++ni) {
            union { unsigned long long q; bf16 hh[4]; } pw;
#pragma unroll
            for (int r = 0; r < 4; ++r) pw.hh[r] = __float2bfloat16(acc[mi][ni][r]);
            *(unsigned long long*)((bf16*)O2 +
                (((size_t)(b * 4 + hv)) * 64 + ni * 16 + l16) * kTP + te0) = pw.q;
          }
        }
      }
    } else {
      // ---- fused SSM prep: X (in acc) vs [dtw;Bw;Cw] of head hd ----
      const int hd = tile - 16;
      __syncthreads();   // all GEMM LDS reads done; smem reusable
      short (*Xl)[72] = (short(*)[72])smem;
      short (*Wl)[72] = (short(*)[72])(smem + 18432);
      // X0 column (d==0) before anything else
#pragma unroll
      for (int mi = 0; mi < 2; ++mi) {
        if (l16 == 0) {
#pragma unroll
          for (int r = 0; r < 4; ++r) {
            int row = bm + wave * 32 + mi * 16 + quad * 4 + r;
            if (row < kMEXT) {
              int bb = row >= kTEXT ? 1 : 0;
              int te = row - bb * kTEXT;
              if (te >= kNMETA) X0[(size_t)(bb * kT + te - kNMETA) * 8 + hd] = acc[mi][0][r];
            }
          }
        }
      }
      // write X tile (C-layout -> LDS rows)
#pragma unroll
      for (int mi = 0; mi < 2; ++mi)
#pragma unroll
        for (int ni = 0; ni < 4; ++ni)
#pragma unroll
          for (int r = 0; r < 4; ++r)
            Xl[wave * 32 + mi * 16 + quad * 4 + r][ni * 16 + l16] = bf2s(acc[mi][ni][r]);
      // stage W48 = [dtw;Bw;Cw] head hd (f32 -> bf16)
      for (int s2 = tid; s2 < 384; s2 += 256) {
        int row = s2 >> 3, v = s2 & 7;
        const float* src = (row < 16) ? dtw + ((size_t)(hd * 16 + row)) * 64
                         : (row < 32) ? Bw + ((size_t)(hd * 16 + row - 16)) * 64
                                      : Cw + ((size_t)(hd * 16 + row - 32)) * 64;
        float4 a0 = ((const float4*)src)[v * 2];
        float4 a1 = ((const float4*)src)[v * 2 + 1];
        *(uint4*)&Wl[row][v * 8] = pack8(a0, a1);
      }
      __syncthreads();
      f32x4 a3[2][3] = {};
#pragma unroll
      for (int mt = 0; mt < 2; ++mt) {
        short8 xa0 = *(const short8*)&Xl[wave * 32 + mt * 16 + l16][quad * 8];
        short8 xa1 = *(const short8*)&Xl[wave * 32 + mt * 16 + l16][32 + quad * 8];
#pragma unroll
        for (int nb = 0; nb < 3; ++nb) {
          short8 wb0 = *(const short8*)&Wl[nb * 16 + l16][quad * 8];
          a3[mt][nb] = __builtin_amdgcn_mfma_f32_16x16x32_bf16(xa0, wb0, a3[mt][nb], 0, 0, 0);
          short8 wb1 = *(const short8*)&Wl[nb * 16 + l16][32 + quad * 8];
          a3[mt][nb] = __builtin_amdgcn_mfma_f32_16x16x32_bf16(xa1, wb1, a3[mt][nb], 0, 0, 0);
        }
      }
      float dtb_v = dtb[hd * 16 + l16];
      float A_v = fminf(-expf(logA[hd * 16 + l16]), 10.f);
#pragma unroll
      for (int mt = 0; mt < 2; ++mt)
#pragma unroll
        for (int r = 0; r < 4; ++r) {
          int row = bm + wave * 32 + mt * 16 + quad * 4 + r;
          if (row >= kMEXT) continue;
          int bb = row >= kTEXT ? 1 : 0;
          int te = row - bb * kTEXT;
          if (te < kNMETA) continue;
          size_t ix = (size_t)(bb * kT + te - kNMETA) * 128 + hd * 16 + l16;
          float raw = a3[mt][0][r] + dtb_v;
          float sp = fmaxf(raw, 0.f) + log1pf(expf(-fabsf(raw)));   // stable softplus
          float dt = fminf(sp, 1.f);
          float lav = fminf(fmaxf(dt * A_v, -0.5f), 0.f);
          *(float2*)(LU + 2 * ix) = make_float2(lav, a3[mt][1][r] * dt);
          CC[ix] = a3[mt][2][r];
        }
    }
  }
}

// ------- MFMA flash attention, kv-split x2: partial O (unscaled) + l to f32 buffers -------
__global__ __launch_bounds__(256) void attn_part(const bf16* __restrict__ Qp,
                                                 const bf16* __restrict__ Kp,
                                                 const bf16* __restrict__ Vt,
                                                 float* __restrict__ AO, float* __restrict__ AL) {
  __shared__ short Ks[64][72];
  __shared__ short Vs[64][72];
  __shared__ short Ps[4][16][72];
  const int part = blockIdx.x & 1;
  const int qt = (kQT - 1) - (blockIdx.x >> 1);   // longest first
  const int h = blockIdx.y, b = blockIdx.z;
  const int kvh = h >> 1;
  const int tid = threadIdx.x, wave = tid >> 6, lane = tid & 63;
  const int quad = lane >> 4, l16 = lane & 15;
  const int hsplit = (qt + 2) >> 1;
  const int kt_begin = part == 0 ? 0 : hsplit;
  const int kt_end = part == 0 ? hsplit : qt + 1;   // exclusive

  short8 qf[2];
  {
    const bf16* qrow = Qp + (((size_t)(b * 8 + h)) * kTP + qt * 64 + wave * 16 + l16) * 64 + quad * 8;
    qf[0] = *(const short8*)(qrow);
    qf[1] = *(const short8*)(qrow + 32);
  }
  short8 ones;
#pragma unroll
  for (int i = 0; i < 8; ++i) ones[i] = (short)0x3F80;   // bf16 1.0

  const bf16* kbase = Kp + ((size_t)(b * 4 + kvh)) * kTP * 64;
  const bf16* vbase = Vt + ((size_t)(b * 4 + kvh)) * 64 * kTP;

  const int r0row = tid >> 3, r0c8 = tid & 7;
  const int r1row = (256 + tid) >> 3, r1c8 = tid & 7;

  f32x4 O[4] = {};
  f32x4 lacc = {};
  const int q_abs = qt * 64 + wave * 16 + l16;

  uint4 kr0 = *(const uint4*)(kbase + (size_t)(kt_begin * 64 + r0row) * 64 + r0c8 * 8);
  uint4 kr1 = *(const uint4*)(kbase + (size_t)(kt_begin * 64 + r1row) * 64 + r1c8 * 8);
  uint4 vr0 = *(const uint4*)(vbase + (size_t)r0row * kTP + kt_begin * 64 + r0c8 * 8);
  uint4 vr1 = *(const uint4*)(vbase + (size_t)r1row * kTP + kt_begin * 64 + r1c8 * 8);

  for (int kt = kt_begin; kt < kt_end; ++kt) {
    __syncthreads();
    *(uint4*)&Ks[r0row][r0c8 * 8] = kr0;
    *(uint4*)&Ks[r1row][r1c8 * 8] = kr1;
    *(uint4*)&Vs[r0row][r0c8 * 8] = vr0;
    *(uint4*)&Vs[r1row][r1c8 * 8] = vr1;
    if (kt + 1 < kt_end) {
      int kn = (kt + 1) * 64;
      kr0 = *(const uint4*)(kbase + (size_t)(kn + r0row) * 64 + r0c8 * 8);
      kr1 = *(const uint4*)(kbase + (size_t)(kn + r1row) * 64 + r1c8 * 8);
      vr0 = *(const uint4*)(vbase + (size_t)r0row * kTP + kn + r0c8 * 8);
      vr1 = *(const uint4*)(vbase + (size_t)r1row * kTP + kn + r1c8 * 8);
    }
    __syncthreads();

    f32x4 st[4] = {};
#pragma unroll
    for (int nb = 0; nb < 4; ++nb) {
      short8 ak0 = *(const short8*)&Ks[nb * 16 + l16][quad * 8];
      st[nb] = __builtin_amdgcn_mfma_f32_16x16x32_bf16(ak0, qf[0], st[nb], 0, 0, 0);
      short8 ak1 = *(const short8*)&Ks[nb * 16 + l16][32 + quad * 8];
      st[nb] = __builtin_amdgcn_mfma_f32_16x16x32_bf16(ak1, qf[1], st[nb], 0, 0, 0);
    }
    if (kt == qt) {
      int key0 = kt * 64 + quad * 4;
#pragma unroll
      for (int nb = 0; nb < 4; ++nb)
#pragma unroll
        for (int rg = 0; rg < 4; ++rg)
          if (key0 + nb * 16 + rg > q_abs) st[nb][rg] = -1e30f;
    }
#pragma unroll
    for (int nb = 0; nb < 4; ++nb) {
      union { unsigned long long q; bf16 hh[4]; } pw;
#pragma unroll
      for (int rg = 0; rg < 4; ++rg) pw.hh[rg] = __float2bfloat16(__expf(st[nb][rg]));
      *(unsigned long long*)&Ps[wave][l16][nb * 16 + quad * 4] = pw.q;
    }
    short8 pf0 = *(const short8*)&Ps[wave][l16][quad * 8];
    short8 pf1 = *(const short8*)&Ps[wave][l16][32 + quad * 8];
    lacc = __builtin_amdgcn_mfma_f32_16x16x32_bf16(pf0, ones, lacc, 0, 0, 0);
    lacc = __builtin_amdgcn_mfma_f32_16x16x32_bf16(pf1, ones, lacc, 0, 0, 0);
#pragma unroll
    for (int db = 0; db < 4; ++db) {
      short8 bv0 = *(const short8*)&Vs[db * 16 + l16][quad * 8];
      O[db] = __builtin_amdgcn_mfma_f32_16x16x32_bf16(pf0, bv0, O[db], 0, 0, 0);
      short8 bv1 = *(const short8*)&Vs[db * 16 + l16][32 + quad * 8];
      O[db] = __builtin_amdgcn_mfma_f32_16x16x32_bf16(pf1, bv1, O[db], 0, 0, 0);
    }
  }
  size_t hb = (((size_t)part * 2 + b) * 8 + h);
  float* aoB = AO + hb * kTP * 64;
  float* alB = AL + hb * kTP;
#pragma unroll
  for (int rg = 0; rg < 4; ++rg) {
    int q = qt * 64 + wave * 16 + quad * 4 + rg;
    float* dst = aoB + (size_t)q * 64 + l16;
#pragma unroll
    for (int db = 0; db < 4; ++db) dst[db * 16] = O[db][rg];
    if (l16 == 0) alB[q] = lacc[rg];
  }
}

// ------- fused scan: pass1 local (H,P) per 32-sub-chunk; wave Hillis-Steele; pass2 final h ----
// grid 64 blocks x 256; block = 4 chains (b,hs); wave w scans chain w.
__global__ __launch_bounds__(256) void ssm_scan(const float* __restrict__ LU, bf16* __restrict__ HL) {
  __shared__ float sH[4][64], sP[4][64], sH0[4][64];
  const int tid = threadIdx.x;
  const int ch = tid & 3, c = tid >> 2;
  const int chain = blockIdx.x * 4 + ch;       // 0..255
  const int b = chain >> 7, hs = chain & 127;
  const float2* LU2 = (const float2*)LU;
  const size_t base = ((size_t)b * kT) * 128 + hs;
  float H = 0.f, cum = 0.f;
  for (int i = 0; i < 32; ++i) {
    float2 lu = LU2[base + (size_t)(c * 32 + i) * 128];
    cum += lu.x;
    H = __expf(lu.x) * H + lu.y;
  }
  sH[ch][c] = H;
  sP[ch][c] = __expf(cum);       // cum >= -16, no clip needed
  __syncthreads();
  const int wv = tid >> 6, lane = tid & 63;
  float Hs = sH[wv][lane], Ps = sP[wv][lane];
#pragma unroll
  for (int off = 1; off < 64; off <<= 1) {
    float Hp = __shfl_up(Hs, off, 64);
    float Pp = __shfl_up(Ps, off, 64);
    if (lane >= off) { Hs = Hs + Ps * Hp; Ps = Ps * Pp; }
  }
  float Hex = __shfl_up(Hs, 1, 64);
  if (lane == 0) Hex = 0.f;
  sH0[wv][lane] = Hex;
  __syncthreads();
  float h = sH0[ch][c];          // exclusive prefix = h entering this sub-chunk
  for (int i = 0; i < 32; ++i) {
    size_t ix = base + (size_t)(c * 32 + i) * 128;
    float2 lu = LU2[ix];
    h = __expf(lu.x) * h + lu.y;
    HL[ix] = __float2bfloat16(h);
  }
}

// ------- fused: attn kv-split combine (blocks 0..527) + ssm output (blocks 528..1039) -------
__global__ __launch_bounds__(256) void combine_out(const float* __restrict__ AO,
                                                   const float* __restrict__ AL,
                                                   const float* __restrict__ attn_scale,
                                                   const bf16* __restrict__ HL, const float* __restrict__ CC,
                                                   const float* __restrict__ X0, const float* __restrict__ Ow,
                                                   const float* __restrict__ ssm_scale,
                                                   bf16* __restrict__ Y) {
  if (blockIdx.x < 528) {
    int id = blockIdx.x * 256 + threadIdx.x;     // 2*8*2112*4
    int d16 = id & 3;
    int tmp = id >> 2;
    int q = tmp % kTP; tmp /= kTP;
    int h = tmp & 7, b = tmp >> 3;
    if (q < kNMETA || q >= kTEXT) return;
    size_t hb0 = ((size_t)b * 8 + h), hb1 = ((size_t)(2 + b) * 8 + h);
    float l = AL[hb0 * kTP + q] + AL[hb1 * kTP + q];
    float so = attn_scale[0] / fmaxf(l, 1e-30f);
    const float4* p0 = (const float4*)(AO + (hb0 * kTP + q) * 64 + d16 * 16);
    const float4* p1 = (const float4*)(AO + (hb1 * kTP + q) * 64 + d16 * 16);
    bf16* dst = Y + ((size_t)(b * kT + q - kNMETA)) * kDIM + h * 64 + d16 * 16;
#pragma unroll
    for (int i = 0; i < 4; ++i) {
      float4 a = p0[i], c = p1[i];
      dst[i * 4 + 0] = __float2bfloat16((a.x + c.x) * so);
      dst[i * 4 + 1] = __float2bfloat16((a.y + c.y) * so);
      dst[i * 4 + 2] = __float2bfloat16((a.z + c.z) * so);
      dst[i * 4 + 3] = __float2bfloat16((a.w + c.w) * so);
    }
  } else {
    int id = (blockIdx.x - 528) * 256 + threadIdx.x;   // kMX*32
    int d4 = id & 3, h = (id >> 2) & 7, t = (id >> 5) & 2047, b = id >> 16;
    size_t ix0 = ((size_t)(b * kT + t)) * 128 + h * 16;
    float hv[16], y = 0.f;
#pragma unroll
    for (int s = 0; s < 16; ++s) {
      float v = __bfloat162float(HL[ix0 + s]);
      hv[s] = v;
      y += CC[ix0 + s] * v;
    }
    float x0 = X0[(size_t)(b * kT + t) * 8 + h];
    float scl = ssm_scale[0];
    const float* ow = Ow + ((size_t)h * 64 + d4 * 16) * 16;
    bf16* dst = Y + ((size_t)(b * kT + t)) * kDIM + 512 + h * 64 + d4 * 16;
    float yx = y * x0;
#pragma unroll
    for (int d = 0; d < 16; ++d) {
      float acc = yx;
      const float* owr = ow + d * 16;
#pragma unroll
      for (int s = 0; s < 16; ++s) acc += hv[s] * owr[s];
      dst[d] = __float2bfloat16(acc * scl);
    }
  }
}

// ---------------- host ----------------
extern "C" void kernel_launch(void* const* d_in, const int* in_sizes, int n_in,
                              void* d_out, int out_size, void* d_ws, size_t ws_size,
                              hipStream_t stream) {
  (void)in_sizes; (void)n_in; (void)out_size; (void)ws_size;
  const float* x        = (const float*)d_in[0];
  const float* meta     = (const float*)d_in[1];
  const float* c_q_w    = (const float*)d_in[2];
  const float* c_k_w    = (const float*)d_in[3];
  const float* c_v_w    = (const float*)d_in[4];
  const float* q_gain   = (const float*)d_in[5];
  const float* ssm_in_w = (const float*)d_in[6];
  const float* proj_w   = (const float*)d_in[7];
  const float* attn_sc  = (const float*)d_in[8];
  const float* ssm_sc   = (const float*)d_in[9];
  const float* ssm_logA = (const float*)d_in[10];
  const float* ssm_Bw   = (const float*)d_in[11];
  const float* ssm_Cw   = (const float*)d_in[12];
  const float* ssm_dtw  = (const float*)d_in[13];
  const float* ssm_dtb  = (const float*)d_in[14];
  const float* ssm_Ow   = (const float*)d_in[15];

  char* w = (char*)d_ws;
  bf16*  XE = (bf16*)(w + oXE);
  bf16*  YB = (bf16*)(w + oYB);
  bf16*  QP = (bf16*)(w + oQP);
  bf16*  KP = (bf16*)(w + oKP);
  bf16*  VT = (bf16*)(w + oVT);
  bf16*  WQ = (bf16*)(w + oWQ);
  bf16*  WP = (bf16*)(w + oWP);
  float* LU = (float*)(w + oLU);
  float* CC = (float*)(w + oCC);
  bf16*  HL = (bf16*)(w + oHL);
  float* X0 = (float*)(w + oX0);
  float* AO = (float*)(w + oAO);
  float* AL = (float*)(w + oAL);

  prep_all<<<3632, 256, 0, stream>>>(c_q_w, c_k_w, c_v_w, ssm_in_w, proj_w,
                                     x, meta, WQ, WP, XE, QP, KP, VT);

  // QKV + SSM-prep fused GEMM
  gemm_t<0><<<dim3(24, kMPAD / 128), 256, 0, stream>>>(XE, WQ, QP, KP, VT, q_gain,
                                                       ssm_dtw, ssm_dtb, ssm_Bw, ssm_Cw,
                                                       ssm_logA, LU, CC, X0);

  attn_part<<<dim3(kQT * 2, 8, kB), 256, 0, stream>>>(QP, KP, VT, AO, AL);

  ssm_scan<<<64, 256, 0, stream>>>(LU, HL);

  combine_out<<<1040, 256, 0, stream>>>(AO, AL, attn_sc, HL, CC, X0, ssm_Ow, ssm_sc, YB);

  gemm_t<2><<<dim3(16, kMX / 128), 256, 0, stream>>>(YB, WP, d_out, nullptr, nullptr, nullptr,
                                                     nullptr, nullptr, nullptr, nullptr, nullptr,
                                                     nullptr, nullptr, nullptr);
}

// Round 13
// 213.766 us; speedup vs baseline: 1.0614x; 1.0614x over previous
//
#include <hip/hip_runtime.h>
#include <hip/hip_bf16.h>
#include <math.h>

typedef __hip_bfloat16 bf16;
typedef __attribute__((ext_vector_type(8))) short short8;   // 8 bf16 = 4 VGPRs (MFMA A/B frag)
typedef __attribute__((ext_vector_type(4))) float f32x4;    // MFMA C/D frag

static constexpr int kB = 2;
static constexpr int kT = 2048;
static constexpr int kDIM = 1024;
static constexpr int kNMETA = 4;
static constexpr int kTEXT = kT + kNMETA;   // 2052
static constexpr int kMEXT = kB * kTEXT;    // 4104
static constexpr int kMPAD = 4224;          // 33*128
static constexpr int kMX = kB * kT;         // 4096
static constexpr int kQT = 33;
static constexpr int kTP = 2112;            // 33*64

// ---------- workspace layout (bytes); ws ~268 MB ----------
static constexpr size_t oXE = 0;                                  // x_ext bf16 [4224][1024]
static constexpr size_t oYB = 0;                                  // aliases XE (dead after GEMMs)
static constexpr size_t oLU = 8650752;                            // la/u interleaved f32x2 [4096][128]
static constexpr size_t oCC = oLU + (size_t)kMX * 128 * 8;        // Cc f32 [4096][128]
static constexpr size_t oHL = oCC + (size_t)kMX * 128 * 4;        // final h bf16 [4096][128]
static constexpr size_t oX0 = oHL + (size_t)kMX * 128 * 2;        // x0 f32 [4096][8]
static constexpr size_t oQP = oX0 + (size_t)kMX * 8 * 4;          // Qp bf16 [b][8][2112][64]
static constexpr size_t oKP = oQP + (size_t)kB * 8 * kTP * 64 * 2;// Kp bf16 [b][4][2112][64]
static constexpr size_t oVT = oKP + (size_t)kB * 4 * kTP * 64 * 2;// Vt bf16 [b][4][64][2112]
static constexpr size_t oWP = oVT + (size_t)kB * 4 * 64 * kTP * 2;// Wproj bf16 [1024][1024]
static constexpr size_t oWQ = oWP + (size_t)1024 * 1024 * 2;      // WQKV+WSX bf16 [1536][1024]
static constexpr size_t oAO = 134217728;                          // attn partial O f32 [3][b][8][2112][64]
static constexpr size_t oAL = oAO + (size_t)3 * kB * 8 * kTP * 64 * 4;  // partial l f32 [3][b][8][2112]

#define GLD_LDS16(gp, lp)                                                          \
  __builtin_amdgcn_global_load_lds((const __attribute__((address_space(1))) void*)(gp), \
                                   (__attribute__((address_space(3))) void*)(lp), 16, 0, 0)

__device__ __forceinline__ short bf2s(float f) {
  union { bf16 h; short s; } u;
  u.h = __float2bfloat16(f);
  return u.s;
}

__device__ __forceinline__ uint4 pack8(float4 a, float4 b) {
  union { bf16 h[8]; uint4 v; } u;
  u.h[0] = __float2bfloat16(a.x); u.h[1] = __float2bfloat16(a.y);
  u.h[2] = __float2bfloat16(a.z); u.h[3] = __float2bfloat16(a.w);
  u.h[4] = __float2bfloat16(b.x); u.h[5] = __float2bfloat16(b.y);
  u.h[6] = __float2bfloat16(b.z); u.h[7] = __float2bfloat16(b.w);
  return u.v;
}

// ---- prep: weight converts + x_ext build + QP/KP/VT tail zeroing, one launch ----
__global__ __launch_bounds__(256) void prep_all(const float* __restrict__ cq, const float* __restrict__ ck,
                                                const float* __restrict__ cv, const float* __restrict__ sw,
                                                const float* __restrict__ pw,
                                                const float* __restrict__ x, const float* __restrict__ meta,
                                                bf16* __restrict__ wqkvsx, bf16* __restrict__ wproj,
                                                bf16* __restrict__ xe,
                                                bf16* __restrict__ Qp, bf16* __restrict__ Kp,
                                                bf16* __restrict__ Vt) {
  int i = blockIdx.x * 256 + threadIdx.x;
  if (i < 327680) {                       // seg0: weights
    int row = i >> 7, v = i & 127;
    const float* src; bf16* dst;
    if (row < 512)       { src = cq + (size_t)row * 1024;          dst = wqkvsx + (size_t)row * 1024; }
    else if (row < 768)  { src = ck + (size_t)(row - 512) * 1024;  dst = wqkvsx + (size_t)row * 1024; }
    else if (row < 1024) { src = cv + (size_t)(row - 768) * 1024;  dst = wqkvsx + (size_t)row * 1024; }
    else if (row < 1536) { src = sw + (size_t)(row - 1024) * 1024; dst = wqkvsx + (size_t)row * 1024; }
    else                 { src = pw + (size_t)(row - 1536) * 1024; dst = wproj + (size_t)(row - 1536) * 1024; }
    float4 a0 = ((const float4*)src)[v * 2], a1 = ((const float4*)src)[v * 2 + 1];
    ((uint4*)dst)[v] = pack8(a0, a1);
  } else if (i < 868352) {                // seg1: x_ext
    int j = i - 327680;
    int r = j >> 7, v = j & 127;
    uint4 val = {0u, 0u, 0u, 0u};
    if (r < kMEXT) {
      int b = r / kTEXT, te = r - b * kTEXT;
      const float* src = (te < kNMETA) ? (meta + (size_t)te * kDIM)
                                       : (x + ((size_t)b * kT + (te - kNMETA)) * kDIM);
      float4 a0 = ((const float4*)src)[v * 2];
      float4 a1 = ((const float4*)src)[v * 2 + 1];
      val = pack8(a0, a1);
    }
    ((uint4*)(xe + (size_t)r * kDIM))[v] = val;
  } else {                                // seg2: zero pad tails (uint = 2 bf16)
    int j = i - 868352;
    if (j < 30720) {            // QP tails
      int k = j & 31, te = (j >> 5) % 60, bh = j / (60 * 32);
      *(unsigned int*)(Qp + ((size_t)bh * kTP + 2052 + te) * 64 + k * 2) = 0u;
    } else if (j < 46080) {     // KP tails
      int jj = j - 30720;
      int k = jj & 31, te = (jj >> 5) % 60, bh = jj / (60 * 32);
      *(unsigned int*)(Kp + ((size_t)bh * kTP + 2052 + te) * 64 + k * 2) = 0u;
    } else if (j < 61440) {     // VT tails
      int jj = j - 46080;
      int k = jj % 30, rowd = jj / 30;
      *(unsigned int*)(Vt + (size_t)rowd * kTP + 2052 + k * 2) = 0u;
    }
  }
}

// ========== 128x64-tile bf16 GEMM, BK=64 as two BK=32 panels, GLD staging ==========
// LDS: A p0 [0,8K) rows0-127x32, A p1 [8K,16K), B p0 [16K,20K), B p1 [20K,24K).
// MODE 0: fused QKV+SSM-prep epilogue. MODE 2: proj (f32 out).
template <int MODE>
__global__ __launch_bounds__(256) void gemm_t(const bf16* __restrict__ A,
                                              const bf16* __restrict__ W,
                                              void* __restrict__ O0, void* __restrict__ O1,
                                              void* __restrict__ O2,
                                              const float* __restrict__ q_gain,
                                              const float* __restrict__ dtw, const float* __restrict__ dtb,
                                              const float* __restrict__ Bw, const float* __restrict__ Cw,
                                              const float* __restrict__ logA,
                                              float* __restrict__ LU, float* __restrict__ CC,
                                              float* __restrict__ X0) {
  constexpr int SMEM_SZ = (MODE == 0) ? 25344 : 24576;   // MODE0 overlay: X[128][72]+W48[48][72]
  __shared__ char smem[SMEM_SZ];
  const int tid = threadIdx.x;
  const int wave = tid >> 6, lane = tid & 63;
  const int quad = lane >> 4, l16 = lane & 15;
  const int bm = blockIdx.y * 128, bn = blockIdx.x * 64;
  const bf16* ag0 = A + (size_t)(bm + (tid >> 2)) * 1024 + (tid & 3) * 8;        // rows 0..63
  const bf16* ag1 = A + (size_t)(bm + 64 + (tid >> 2)) * 1024 + (tid & 3) * 8;   // rows 64..127
  const bf16* bg0 = W + (size_t)(bn + (tid >> 2)) * 1024 + (tid & 3) * 8;
  char* a00 = smem + wave * 1024;             // A p0, rows 0..63
  char* a10 = smem + 4096 + wave * 1024;      // A p0, rows 64..127
  char* a01 = smem + 8192 + wave * 1024;      // A p1, rows 0..63
  char* a11 = smem + 12288 + wave * 1024;     // A p1, rows 64..127
  char* bs0 = smem + 16384 + wave * 1024;     // B p0
  char* bs1 = smem + 20480 + wave * 1024;     // B p1
  f32x4 acc[2][4] = {};
  for (int k0 = 0; k0 < 1024; k0 += 64) {
    __syncthreads();
    GLD_LDS16(ag0, a00);
    GLD_LDS16(ag0 + 32, a01);
    GLD_LDS16(ag1, a10);
    GLD_LDS16(ag1 + 32, a11);
    GLD_LDS16(bg0, bs0);
    GLD_LDS16(bg0 + 32, bs1);
    ag0 += 64; ag1 += 64; bg0 += 64;
    __syncthreads();
#pragma unroll
    for (int p = 0; p < 2; ++p) {
      short8 af[2], bfr[4];
#pragma unroll
      for (int mi = 0; mi < 2; ++mi)
        af[mi] = *(const short8*)(smem + p * 8192 +
                                  (size_t)(wave * 32 + mi * 16 + l16) * 64 + quad * 16);
#pragma unroll
      for (int ni = 0; ni < 4; ++ni)
        bfr[ni] = *(const short8*)(smem + 16384 + p * 4096 +
                                   (size_t)(ni * 16 + l16) * 64 + quad * 16);
#pragma unroll
      for (int mi = 0; mi < 2; ++mi)
#pragma unroll
        for (int ni = 0; ni < 4; ++ni)
          acc[mi][ni] = __builtin_amdgcn_mfma_f32_16x16x32_bf16(af[mi], bfr[ni], acc[mi][ni], 0, 0, 0);
    }
  }
  // ---- epilogue ----
  if constexpr (MODE == 2) {
#pragma unroll
    for (int mi = 0; mi < 2; ++mi)
#pragma unroll
      for (int ni = 0; ni < 4; ++ni) {
        int colg = bn + ni * 16 + l16;
#pragma unroll
        for (int r = 0; r < 4; ++r) {
          int row = bm + wave * 32 + mi * 16 + quad * 4 + r;
          ((float*)O0)[(size_t)row * 1024 + colg] = acc[mi][ni][r];
        }
      }
  } else {
    const int tile = blockIdx.x;
    if (tile < 16) {
      float gain = (tile < 8) ? q_gain[tile] * 0.125f : 1.f;
      float inv0 = exp2f(-13.287712379549449f * (float)l16 * (1.f / 32.f));
      float inv1 = exp2f(-13.287712379549449f * (float)(l16 + 16) * (1.f / 32.f));
#pragma unroll
      for (int mi = 0; mi < 2; ++mi) {
        int row0 = bm + wave * 32 + mi * 16 + quad * 4;
        if (row0 >= kMEXT) continue;          // 4-row group fully pad
        int b = row0 >= kTEXT ? 1 : 0;
        int te0 = row0 - b * kTEXT;
        if (tile < 12) {
          float ss[4];
#pragma unroll
          for (int r = 0; r < 4; ++r) {
            float s = 0.f;
#pragma unroll
            for (int ni = 0; ni < 4; ++ni) s += acc[mi][ni][r] * acc[mi][ni][r];
#pragma unroll
            for (int off = 1; off < 16; off <<= 1) s += __shfl_xor(s, off, 64);
            ss[r] = s;
          }
          bf16* base = (tile < 8)
            ? (bf16*)O0 + (((size_t)(b * 8 + tile)) * kTP + te0) * 64 + l16
            : (bf16*)O1 + (((size_t)(b * 4 + tile - 8)) * kTP + te0) * 64 + l16;
#pragma unroll
          for (int r = 0; r < 4; ++r) {
            float rn = rsqrtf(ss[r] * (1.f / 64.f) + 1e-6f) * gain;
            float te = (float)(te0 + r);
            float a0 = te * inv0, a1 = te * inv1;
            float c0 = __cosf(a0), s0 = __sinf(a0);
            float c1 = __cosf(a1), s1 = __sinf(a1);
            float v0 = acc[mi][0][r] * rn, v1 = acc[mi][1][r] * rn;
            float v2 = acc[mi][2][r] * rn, v3 = acc[mi][3][r] * rn;
            bf16* dst = base + (size_t)r * 64;
            dst[0]  = __float2bfloat16(v0 * c0 - v2 * s0);
            dst[16] = __float2bfloat16(v1 * c1 - v3 * s1);
            dst[32] = __float2bfloat16(v0 * s0 + v2 * c0);
            dst[48] = __float2bfloat16(v1 * s1 + v3 * c1);
          }
        } else {
          int hv = tile - 12;
#pragma unroll
          for (int ni = 0; ni < 4; ++ni) {
            union { unsigned long long q; bf16 hh[4]; } pw;
#pragma unroll
            for (int r = 0; r < 4; ++r) pw.hh[r] = __float2bfloat16(acc[mi][ni][r]);
            *(unsigned long long*)((bf16*)O2 +
                (((size_t)(b * 4 + hv)) * 64 + ni * 16 + l16) * kTP + te0) = pw.q;
          }
        }
      }
    } else {
      // ---- fused SSM prep: X (in acc) vs [dtw;Bw;Cw] of head hd ----
      const int hd = tile - 16;
      __syncthreads();   // all GEMM LDS reads done; smem reusable
      short (*Xl)[72] = (short(*)[72])smem;
      short (*Wl)[72] = (short(*)[72])(smem + 18432);
#pragma unroll
      for (int mi = 0; mi < 2; ++mi) {
        if (l16 == 0) {
#pragma unroll
          for (int r = 0; r < 4; ++r) {
            int row = bm + wave * 32 + mi * 16 + quad * 4 + r;
            if (row < kMEXT) {
              int bb = row >= kTEXT ? 1 : 0;
              int te = row - bb * kTEXT;
              if (te >= kNMETA) X0[(size_t)(bb * kT + te - kNMETA) * 8 + hd] = acc[mi][0][r];
            }
          }
        }
      }
#pragma unroll
      for (int mi = 0; mi < 2; ++mi)
#pragma unroll
        for (int ni = 0; ni < 4; ++ni)
#pragma unroll
          for (int r = 0; r < 4; ++r)
            Xl[wave * 32 + mi * 16 + quad * 4 + r][ni * 16 + l16] = bf2s(acc[mi][ni][r]);
      for (int s2 = tid; s2 < 384; s2 += 256) {
        int row = s2 >> 3, v = s2 & 7;
        const float* src = (row < 16) ? dtw + ((size_t)(hd * 16 + row)) * 64
                         : (row < 32) ? Bw + ((size_t)(hd * 16 + row - 16)) * 64
                                      : Cw + ((size_t)(hd * 16 + row - 32)) * 64;
        float4 a0 = ((const float4*)src)[v * 2];
        float4 a1 = ((const float4*)src)[v * 2 + 1];
        *(uint4*)&Wl[row][v * 8] = pack8(a0, a1);
      }
      __syncthreads();
      f32x4 a3[2][3] = {};
#pragma unroll
      for (int mt = 0; mt < 2; ++mt) {
        short8 xa0 = *(const short8*)&Xl[wave * 32 + mt * 16 + l16][quad * 8];
        short8 xa1 = *(const short8*)&Xl[wave * 32 + mt * 16 + l16][32 + quad * 8];
#pragma unroll
        for (int nb = 0; nb < 3; ++nb) {
          short8 wb0 = *(const short8*)&Wl[nb * 16 + l16][quad * 8];
          a3[mt][nb] = __builtin_amdgcn_mfma_f32_16x16x32_bf16(xa0, wb0, a3[mt][nb], 0, 0, 0);
          short8 wb1 = *(const short8*)&Wl[nb * 16 + l16][32 + quad * 8];
          a3[mt][nb] = __builtin_amdgcn_mfma_f32_16x16x32_bf16(xa1, wb1, a3[mt][nb], 0, 0, 0);
        }
      }
      float dtb_v = dtb[hd * 16 + l16];
      float A_v = fminf(-expf(logA[hd * 16 + l16]), 10.f);
#pragma unroll
      for (int mt = 0; mt < 2; ++mt)
#pragma unroll
        for (int r = 0; r < 4; ++r) {
          int row = bm + wave * 32 + mt * 16 + quad * 4 + r;
          if (row >= kMEXT) continue;
          int bb = row >= kTEXT ? 1 : 0;
          int te = row - bb * kTEXT;
          if (te < kNMETA) continue;
          size_t ix = (size_t)(bb * kT + te - kNMETA) * 128 + hd * 16 + l16;
          float raw = a3[mt][0][r] + dtb_v;
          float sp = fmaxf(raw, 0.f) + log1pf(expf(-fabsf(raw)));   // stable softplus
          float dt = fminf(sp, 1.f);
          float lav = fminf(fmaxf(dt * A_v, -0.5f), 0.f);
          *(float2*)(LU + 2 * ix) = make_float2(lav, a3[mt][1][r] * dt);
          CC[ix] = a3[mt][2][r];
        }
    }
  }
}

// ------- MFMA flash attention, kv-split x3: partial O (unscaled) + l to f32 buffers -------
__global__ __launch_bounds__(256) void attn_part(const bf16* __restrict__ Qp,
                                                 const bf16* __restrict__ Kp,
                                                 const bf16* __restrict__ Vt,
                                                 float* __restrict__ AO, float* __restrict__ AL) {
  __shared__ short Ks[64][72];
  __shared__ short Vs[64][72];
  __shared__ short Ps[4][16][72];
  const int part = blockIdx.x % 3;
  const int qt = (kQT - 1) - (blockIdx.x / 3);   // longest first
  const int h = blockIdx.y, b = blockIdx.z;
  const int kvh = h >> 1;
  const int tid = threadIdx.x, wave = tid >> 6, lane = tid & 63;
  const int quad = lane >> 4, l16 = lane & 15;
  const int ntiles = qt + 1;
  const int s1 = ntiles / 3, s2 = (2 * ntiles) / 3;
  const int kt_begin = (part == 0) ? 0 : (part == 1 ? s1 : s2);
  const int kt_end = (part == 0) ? s1 : (part == 1 ? s2 : ntiles);   // exclusive
  const int kt_pf = (kt_begin < kt_end) ? kt_begin : 0;              // clamp for empty ranges

  short8 qf[2];
  {
    const bf16* qrow = Qp + (((size_t)(b * 8 + h)) * kTP + qt * 64 + wave * 16 + l16) * 64 + quad * 8;
    qf[0] = *(const short8*)(qrow);
    qf[1] = *(const short8*)(qrow + 32);
  }
  short8 ones;
#pragma unroll
  for (int i = 0; i < 8; ++i) ones[i] = (short)0x3F80;   // bf16 1.0

  const bf16* kbase = Kp + ((size_t)(b * 4 + kvh)) * kTP * 64;
  const bf16* vbase = Vt + ((size_t)(b * 4 + kvh)) * 64 * kTP;

  const int r0row = tid >> 3, r0c8 = tid & 7;
  const int r1row = (256 + tid) >> 3, r1c8 = tid & 7;

  f32x4 O[4] = {};
  f32x4 lacc = {};
  const int q_abs = qt * 64 + wave * 16 + l16;

  uint4 kr0 = *(const uint4*)(kbase + (size_t)(kt_pf * 64 + r0row) * 64 + r0c8 * 8);
  uint4 kr1 = *(const uint4*)(kbase + (size_t)(kt_pf * 64 + r1row) * 64 + r1c8 * 8);
  uint4 vr0 = *(const uint4*)(vbase + (size_t)r0row * kTP + kt_pf * 64 + r0c8 * 8);
  uint4 vr1 = *(const uint4*)(vbase + (size_t)r1row * kTP + kt_pf * 64 + r1c8 * 8);

  for (int kt = kt_begin; kt < kt_end; ++kt) {
    __syncthreads();
    *(uint4*)&Ks[r0row][r0c8 * 8] = kr0;
    *(uint4*)&Ks[r1row][r1c8 * 8] = kr1;
    *(uint4*)&Vs[r0row][r0c8 * 8] = vr0;
    *(uint4*)&Vs[r1row][r1c8 * 8] = vr1;
    if (kt + 1 < kt_end) {
      int kn = (kt + 1) * 64;
      kr0 = *(const uint4*)(kbase + (size_t)(kn + r0row) * 64 + r0c8 * 8);
      kr1 = *(const uint4*)(kbase + (size_t)(kn + r1row) * 64 + r1c8 * 8);
      vr0 = *(const uint4*)(vbase + (size_t)r0row * kTP + kn + r0c8 * 8);
      vr1 = *(const uint4*)(vbase + (size_t)r1row * kTP + kn + r1c8 * 8);
    }
    __syncthreads();

    f32x4 st[4] = {};
#pragma unroll
    for (int nb = 0; nb < 4; ++nb) {
      short8 ak0 = *(const short8*)&Ks[nb * 16 + l16][quad * 8];
      st[nb] = __builtin_amdgcn_mfma_f32_16x16x32_bf16(ak0, qf[0], st[nb], 0, 0, 0);
      short8 ak1 = *(const short8*)&Ks[nb * 16 + l16][32 + quad * 8];
      st[nb] = __builtin_amdgcn_mfma_f32_16x16x32_bf16(ak1, qf[1], st[nb], 0, 0, 0);
    }
    if (kt == qt) {
      int key0 = kt * 64 + quad * 4;
#pragma unroll
      for (int nb = 0; nb < 4; ++nb)
#pragma unroll
        for (int rg = 0; rg < 4; ++rg)
          if (key0 + nb * 16 + rg > q_abs) st[nb][rg] = -1e30f;
    }
#pragma unroll
    for (int nb = 0; nb < 4; ++nb) {
      union { unsigned long long q; bf16 hh[4]; } pw;
#pragma unroll
      for (int rg = 0; rg < 4; ++rg) pw.hh[rg] = __float2bfloat16(__expf(st[nb][rg]));
      *(unsigned long long*)&Ps[wave][l16][nb * 16 + quad * 4] = pw.q;
    }
    short8 pf0 = *(const short8*)&Ps[wave][l16][quad * 8];
    short8 pf1 = *(const short8*)&Ps[wave][l16][32 + quad * 8];
    lacc = __builtin_amdgcn_mfma_f32_16x16x32_bf16(pf0, ones, lacc, 0, 0, 0);
    lacc = __builtin_amdgcn_mfma_f32_16x16x32_bf16(pf1, ones, lacc, 0, 0, 0);
#pragma unroll
    for (int db = 0; db < 4; ++db) {
      short8 bv0 = *(const short8*)&Vs[db * 16 + l16][quad * 8];
      O[db] = __builtin_amdgcn_mfma_f32_16x16x32_bf16(pf0, bv0, O[db], 0, 0, 0);
      short8 bv1 = *(const short8*)&Vs[db * 16 + l16][32 + quad * 8];
      O[db] = __builtin_amdgcn_mfma_f32_16x16x32_bf16(pf1, bv1, O[db], 0, 0, 0);
    }
  }
  size_t hb = (((size_t)part * 2 + b) * 8 + h);
  float* aoB = AO + hb * kTP * 64;
  float* alB = AL + hb * kTP;
#pragma unroll
  for (int rg = 0; rg < 4; ++rg) {
    int q = qt * 64 + wave * 16 + quad * 4 + rg;
    float* dst = aoB + (size_t)q * 64 + l16;
#pragma unroll
    for (int db = 0; db < 4; ++db) dst[db * 16] = O[db][rg];
    if (l16 == 0) alB[q] = lacc[rg];
  }
}

// ------- fused scan: pass1 local (H,P) per 32-sub-chunk; wave Hillis-Steele; pass2 final h ----
__global__ __launch_bounds__(256) void ssm_scan(const float* __restrict__ LU, bf16* __restrict__ HL) {
  __shared__ float sH[4][64], sP[4][64], sH0[4][64];
  const int tid = threadIdx.x;
  const int ch = tid & 3, c = tid >> 2;
  const int chain = blockIdx.x * 4 + ch;       // 0..255
  const int b = chain >> 7, hs = chain & 127;
  const float2* LU2 = (const float2*)LU;
  const size_t base = ((size_t)b * kT) * 128 + hs;
  float H = 0.f, cum = 0.f;
  for (int i = 0; i < 32; ++i) {
    float2 lu = LU2[base + (size_t)(c * 32 + i) * 128];
    cum += lu.x;
    H = __expf(lu.x) * H + lu.y;
  }
  sH[ch][c] = H;
  sP[ch][c] = __expf(cum);       // cum >= -16, no clip needed
  __syncthreads();
  const int wv = tid >> 6, lane = tid & 63;
  float Hs = sH[wv][lane], Ps = sP[wv][lane];
#pragma unroll
  for (int off = 1; off < 64; off <<= 1) {
    float Hp = __shfl_up(Hs, off, 64);
    float Pp = __shfl_up(Ps, off, 64);
    if (lane >= off) { Hs = Hs + Ps * Hp; Ps = Ps * Pp; }
  }
  float Hex = __shfl_up(Hs, 1, 64);
  if (lane == 0) Hex = 0.f;
  sH0[wv][lane] = Hex;
  __syncthreads();
  float h = sH0[ch][c];          // exclusive prefix = h entering this sub-chunk
  for (int i = 0; i < 32; ++i) {
    size_t ix = base + (size_t)(c * 32 + i) * 128;
    float2 lu = LU2[ix];
    h = __expf(lu.x) * h + lu.y;
    HL[ix] = __float2bfloat16(h);
  }
}

// ------- fused: attn kv-split combine (blocks 0..527) + ssm output (blocks 528..1039) -------
__global__ __launch_bounds__(256) void combine_out(const float* __restrict__ AO,
                                                   const float* __restrict__ AL,
                                                   const float* __restrict__ attn_scale,
                                                   const bf16* __restrict__ HL, const float* __restrict__ CC,
                                                   const float* __restrict__ X0, const float* __restrict__ Ow,
                                                   const float* __restrict__ ssm_scale,
                                                   bf16* __restrict__ Y) {
  if (blockIdx.x < 528) {
    int id = blockIdx.x * 256 + threadIdx.x;     // 2*8*2112*4
    int d16 = id & 3;
    int tmp = id >> 2;
    int q = tmp % kTP; tmp /= kTP;
    int h = tmp & 7, b = tmp >> 3;
    if (q < kNMETA || q >= kTEXT) return;
    size_t hb0 = ((size_t)b * 8 + h), hb1 = ((size_t)(2 + b) * 8 + h), hb2 = ((size_t)(4 + b) * 8 + h);
    float l = AL[hb0 * kTP + q] + AL[hb1 * kTP + q] + AL[hb2 * kTP + q];
    float so = attn_scale[0] / fmaxf(l, 1e-30f);
    const float4* p0 = (const float4*)(AO + (hb0 * kTP + q) * 64 + d16 * 16);
    const float4* p1 = (const float4*)(AO + (hb1 * kTP + q) * 64 + d16 * 16);
    const float4* p2 = (const float4*)(AO + (hb2 * kTP + q) * 64 + d16 * 16);
    bf16* dst = Y + ((size_t)(b * kT + q - kNMETA)) * kDIM + h * 64 + d16 * 16;
#pragma unroll
    for (int i = 0; i < 4; ++i) {
      float4 a = p0[i], c = p1[i], e = p2[i];
      dst[i * 4 + 0] = __float2bfloat16((a.x + c.x + e.x) * so);
      dst[i * 4 + 1] = __float2bfloat16((a.y + c.y + e.y) * so);
      dst[i * 4 + 2] = __float2bfloat16((a.z + c.z + e.z) * so);
      dst[i * 4 + 3] = __float2bfloat16((a.w + c.w + e.w) * so);
    }
  } else {
    int id = (blockIdx.x - 528) * 256 + threadIdx.x;   // kMX*32
    int d4 = id & 3, h = (id >> 2) & 7, t = (id >> 5) & 2047, b = id >> 16;
    size_t ix0 = ((size_t)(b * kT + t)) * 128 + h * 16;
    float hv[16], y = 0.f;
#pragma unroll
    for (int s = 0; s < 16; ++s) {
      float v = __bfloat162float(HL[ix0 + s]);
      hv[s] = v;
      y += CC[ix0 + s] * v;
    }
    float x0 = X0[(size_t)(b * kT + t) * 8 + h];
    float scl = ssm_scale[0];
    const float* ow = Ow + ((size_t)h * 64 + d4 * 16) * 16;
    bf16* dst = Y + ((size_t)(b * kT + t)) * kDIM + 512 + h * 64 + d4 * 16;
    float yx = y * x0;
#pragma unroll
    for (int d = 0; d < 16; ++d) {
      float acc = yx;
      const float* owr = ow + d * 16;
#pragma unroll
      for (int s = 0; s < 16; ++s) acc += hv[s] * owr[s];
      dst[d] = __float2bfloat16(acc * scl);
    }
  }
}

// ---------------- host ----------------
extern "C" void kernel_launch(void* const* d_in, const int* in_sizes, int n_in,
                              void* d_out, int out_size, void* d_ws, size_t ws_size,
                              hipStream_t stream) {
  (void)in_sizes; (void)n_in; (void)out_size; (void)ws_size;
  const float* x        = (const float*)d_in[0];
  const float* meta     = (const float*)d_in[1];
  const float* c_q_w    = (const float*)d_in[2];
  const float* c_k_w    = (const float*)d_in[3];
  const float* c_v_w    = (const float*)d_in[4];
  const float* q_gain   = (const float*)d_in[5];
  const float* ssm_in_w = (const float*)d_in[6];
  const float* proj_w   = (const float*)d_in[7];
  const float* attn_sc  = (const float*)d_in[8];
  const float* ssm_sc   = (const float*)d_in[9];
  const float* ssm_logA = (const float*)d_in[10];
  const float* ssm_Bw   = (const float*)d_in[11];
  const float* ssm_Cw   = (const float*)d_in[12];
  const float* ssm_dtw  = (const float*)d_in[13];
  const float* ssm_dtb  = (const float*)d_in[14];
  const float* ssm_Ow   = (const float*)d_in[15];

  char* w = (char*)d_ws;
  bf16*  XE = (bf16*)(w + oXE);
  bf16*  YB = (bf16*)(w + oYB);
  bf16*  QP = (bf16*)(w + oQP);
  bf16*  KP = (bf16*)(w + oKP);
  bf16*  VT = (bf16*)(w + oVT);
  bf16*  WQ = (bf16*)(w + oWQ);
  bf16*  WP = (bf16*)(w + oWP);
  float* LU = (float*)(w + oLU);
  float* CC = (float*)(w + oCC);
  bf16*  HL = (bf16*)(w + oHL);
  float* X0 = (float*)(w + oX0);
  float* AO = (float*)(w + oAO);
  float* AL = (float*)(w + oAL);

  prep_all<<<3632, 256, 0, stream>>>(c_q_w, c_k_w, c_v_w, ssm_in_w, proj_w,
                                     x, meta, WQ, WP, XE, QP, KP, VT);

  // QKV + SSM-prep fused GEMM
  gemm_t<0><<<dim3(24, kMPAD / 128), 256, 0, stream>>>(XE, WQ, QP, KP, VT, q_gain,
                                                       ssm_dtw, ssm_dtb, ssm_Bw, ssm_Cw,
                                                       ssm_logA, LU, CC, X0);

  attn_part<<<dim3(kQT * 3, 8, kB), 256, 0, stream>>>(QP, KP, VT, AO, AL);

  ssm_scan<<<64, 256, 0, stream>>>(LU, HL);

  combine_out<<<1040, 256, 0, stream>>>(AO, AL, attn_sc, HL, CC, X0, ssm_Ow, ssm_sc, YB);

  gemm_t<2><<<dim3(16, kMX / 128), 256, 0, stream>>>(YB, WP, d_out, nullptr, nullptr, nullptr,
                                                     nullptr, nullptr, nullptr, nullptr, nullptr,
                                                     nullptr, nullptr, nullptr);
}

// Round 14
// 198.185 us; speedup vs baseline: 1.1448x; 1.0786x over previous
//
#include <hip/hip_runtime.h>
#include <hip/hip_bf16.h>
#include <math.h>

typedef __hip_bfloat16 bf16;
typedef __attribute__((ext_vector_type(8))) short short8;   // 8 bf16 = 4 VGPRs (MFMA A/B frag)
typedef __attribute__((ext_vector_type(4))) float f32x4;    // MFMA C/D frag

static constexpr int kB = 2;
static constexpr int kT = 2048;
static constexpr int kDIM = 1024;
static constexpr int kNMETA = 4;
static constexpr int kTEXT = kT + kNMETA;   // 2052
static constexpr int kMEXT = kB * kTEXT;    // 4104
static constexpr int kMPAD = 4224;          // 33*128
static constexpr int kMX = kB * kT;         // 4096
static constexpr int kQT = 33;
static constexpr int kTP = 2112;            // 33*64

// ---------- workspace layout (bytes); ws ~268 MB ----------
static constexpr size_t oXE = 0;                                  // x_ext bf16 [4224][1024]
static constexpr size_t oYB = 0;                                  // aliases XE (dead after GEMMs)
static constexpr size_t oLU = 8650752;                            // la/u interleaved f32x2 [4096][128]
static constexpr size_t oCC = oLU + (size_t)kMX * 128 * 8;        // Cc f32 [4096][128]
static constexpr size_t oHL = oCC + (size_t)kMX * 128 * 4;        // final h bf16 [4096][128]
static constexpr size_t oX0 = oHL + (size_t)kMX * 128 * 2;        // x0 f32 [4096][8]
static constexpr size_t oQP = oX0 + (size_t)kMX * 8 * 4;          // Qp bf16 [b][8][2112][64]
static constexpr size_t oKP = oQP + (size_t)kB * 8 * kTP * 64 * 2;// Kp bf16 [b][4][2112][64]
static constexpr size_t oVT = oKP + (size_t)kB * 4 * kTP * 64 * 2;// Vt bf16 [b][4][64][2112]
static constexpr size_t oWP = oVT + (size_t)kB * 4 * 64 * kTP * 2;// Wproj bf16 [1024][1024]
static constexpr size_t oWQ = oWP + (size_t)1024 * 1024 * 2;      // WQKV+WSX bf16 [1536][1024]
static constexpr size_t oAO = 134217728;                          // attn partial O f32 [3][b][8][2112][64]
static constexpr size_t oAL = oAO + (size_t)3 * kB * 8 * kTP * 64 * 4;  // partial l f32 [3][b][8][2112]

#define GLD_LDS16(gp, lp)                                                          \
  __builtin_amdgcn_global_load_lds((const __attribute__((address_space(1))) void*)(gp), \
                                   (__attribute__((address_space(3))) void*)(lp), 16, 0, 0)

__device__ __forceinline__ short bf2s(float f) {
  union { bf16 h; short s; } u;
  u.h = __float2bfloat16(f);
  return u.s;
}

__device__ __forceinline__ uint4 pack8(float4 a, float4 b) {
  union { bf16 h[8]; uint4 v; } u;
  u.h[0] = __float2bfloat16(a.x); u.h[1] = __float2bfloat16(a.y);
  u.h[2] = __float2bfloat16(a.z); u.h[3] = __float2bfloat16(a.w);
  u.h[4] = __float2bfloat16(b.x); u.h[5] = __float2bfloat16(b.y);
  u.h[6] = __float2bfloat16(b.z); u.h[7] = __float2bfloat16(b.w);
  return u.v;
}

// ---- prep: weight converts + x_ext build + QP/KP/VT tail zeroing, one launch ----
__global__ __launch_bounds__(256) void prep_all(const float* __restrict__ cq, const float* __restrict__ ck,
                                                const float* __restrict__ cv, const float* __restrict__ sw,
                                                const float* __restrict__ pw,
                                                const float* __restrict__ x, const float* __restrict__ meta,
                                                bf16* __restrict__ wqkvsx, bf16* __restrict__ wproj,
                                                bf16* __restrict__ xe,
                                                bf16* __restrict__ Qp, bf16* __restrict__ Kp,
                                                bf16* __restrict__ Vt) {
  int i = blockIdx.x * 256 + threadIdx.x;
  if (i < 327680) {                       // seg0: weights
    int row = i >> 7, v = i & 127;
    const float* src; bf16* dst;
    if (row < 512)       { src = cq + (size_t)row * 1024;          dst = wqkvsx + (size_t)row * 1024; }
    else if (row < 768)  { src = ck + (size_t)(row - 512) * 1024;  dst = wqkvsx + (size_t)row * 1024; }
    else if (row < 1024) { src = cv + (size_t)(row - 768) * 1024;  dst = wqkvsx + (size_t)row * 1024; }
    else if (row < 1536) { src = sw + (size_t)(row - 1024) * 1024; dst = wqkvsx + (size_t)row * 1024; }
    else                 { src = pw + (size_t)(row - 1536) * 1024; dst = wproj + (size_t)(row - 1536) * 1024; }
    float4 a0 = ((const float4*)src)[v * 2], a1 = ((const float4*)src)[v * 2 + 1];
    ((uint4*)dst)[v] = pack8(a0, a1);
  } else if (i < 868352) {                // seg1: x_ext
    int j = i - 327680;
    int r = j >> 7, v = j & 127;
    uint4 val = {0u, 0u, 0u, 0u};
    if (r < kMEXT) {
      int b = r / kTEXT, te = r - b * kTEXT;
      const float* src = (te < kNMETA) ? (meta + (size_t)te * kDIM)
                                       : (x + ((size_t)b * kT + (te - kNMETA)) * kDIM);
      float4 a0 = ((const float4*)src)[v * 2];
      float4 a1 = ((const float4*)src)[v * 2 + 1];
      val = pack8(a0, a1);
    }
    ((uint4*)(xe + (size_t)r * kDIM))[v] = val;
  } else {                                // seg2: zero pad tails (uint = 2 bf16)
    int j = i - 868352;
    if (j < 30720) {            // QP tails
      int k = j & 31, te = (j >> 5) % 60, bh = j / (60 * 32);
      *(unsigned int*)(Qp + ((size_t)bh * kTP + 2052 + te) * 64 + k * 2) = 0u;
    } else if (j < 46080) {     // KP tails
      int jj = j - 30720;
      int k = jj & 31, te = (jj >> 5) % 60, bh = jj / (60 * 32);
      *(unsigned int*)(Kp + ((size_t)bh * kTP + 2052 + te) * 64 + k * 2) = 0u;
    } else if (j < 61440) {     // VT tails
      int jj = j - 46080;
      int k = jj % 30, rowd = jj / 30;
      *(unsigned int*)(Vt + (size_t)rowd * kTP + 2052 + k * 2) = 0u;
    }
  }
}

// ========== 128x64-tile bf16 GEMM, BK=64 (2 panels), DOUBLE-BUFFERED GLD, 1 barrier/iter ====
// Each buffer (24 KB): A p0 r0-63 [0,4K) | A p0 r64-127 [4K,8K) | A p1 [8K,16K) | B p0 [16K,20K) | B p1 [20K,24K)
// MODE 0: fused QKV+SSM-prep epilogue. MODE 2: proj (f32 out).
template <int MODE>
__global__ __launch_bounds__(256) void gemm_t(const bf16* __restrict__ A,
                                              const bf16* __restrict__ W,
                                              void* __restrict__ O0, void* __restrict__ O1,
                                              void* __restrict__ O2,
                                              const float* __restrict__ q_gain,
                                              const float* __restrict__ dtw, const float* __restrict__ dtb,
                                              const float* __restrict__ Bw, const float* __restrict__ Cw,
                                              const float* __restrict__ logA,
                                              float* __restrict__ LU, float* __restrict__ CC,
                                              float* __restrict__ X0) {
  __shared__ char smem[49152];             // 2 x 24 KB; MODE0 epilogue overlay (25.3 KB) fits
  const int tid = threadIdx.x;
  const int wave = tid >> 6, lane = tid & 63;
  const int quad = lane >> 4, l16 = lane & 15;
  const int bm = blockIdx.y * 128, bn = blockIdx.x * 64;
  const bf16* ag0 = A + (size_t)(bm + (tid >> 2)) * 1024 + (tid & 3) * 8;        // rows 0..63
  const bf16* ag1 = A + (size_t)(bm + 64 + (tid >> 2)) * 1024 + (tid & 3) * 8;   // rows 64..127
  const bf16* bg0 = W + (size_t)(bn + (tid >> 2)) * 1024 + (tid & 3) * 8;
  f32x4 acc[2][4] = {};
  {  // prefetch iter 0 into buf0
    char* sb = smem + wave * 1024;
    GLD_LDS16(ag0, sb);
    GLD_LDS16(ag1, sb + 4096);
    GLD_LDS16(ag0 + 32, sb + 8192);
    GLD_LDS16(ag1 + 32, sb + 12288);
    GLD_LDS16(bg0, sb + 16384);
    GLD_LDS16(bg0 + 32, sb + 20480);
    ag0 += 64; ag1 += 64; bg0 += 64;
  }
  for (int k = 0; k < 16; ++k) {
    char* cur = smem + (k & 1) * 24576;
    char* nxt = smem + ((k & 1) ^ 1) * 24576;
    __syncthreads();                       // drains vmcnt: cur's loads landed (in flight a full iter)
    if (k < 15) {                          // issue next tile into the other buffer
      char* sb = nxt + wave * 1024;
      GLD_LDS16(ag0, sb);
      GLD_LDS16(ag1, sb + 4096);
      GLD_LDS16(ag0 + 32, sb + 8192);
      GLD_LDS16(ag1 + 32, sb + 12288);
      GLD_LDS16(bg0, sb + 16384);
      GLD_LDS16(bg0 + 32, sb + 20480);
      ag0 += 64; ag1 += 64; bg0 += 64;
    }
#pragma unroll
    for (int p = 0; p < 2; ++p) {
      short8 af[2], bfr[4];
#pragma unroll
      for (int mi = 0; mi < 2; ++mi)
        af[mi] = *(const short8*)(cur + p * 8192 +
                                  (size_t)(wave * 32 + mi * 16 + l16) * 64 + quad * 16);
#pragma unroll
      for (int ni = 0; ni < 4; ++ni)
        bfr[ni] = *(const short8*)(cur + 16384 + p * 4096 +
                                   (size_t)(ni * 16 + l16) * 64 + quad * 16);
#pragma unroll
      for (int mi = 0; mi < 2; ++mi)
#pragma unroll
        for (int ni = 0; ni < 4; ++ni)
          acc[mi][ni] = __builtin_amdgcn_mfma_f32_16x16x32_bf16(af[mi], bfr[ni], acc[mi][ni], 0, 0, 0);
    }
  }
  // ---- epilogue ----
  if constexpr (MODE == 2) {
#pragma unroll
    for (int mi = 0; mi < 2; ++mi)
#pragma unroll
      for (int ni = 0; ni < 4; ++ni) {
        int colg = bn + ni * 16 + l16;
#pragma unroll
        for (int r = 0; r < 4; ++r) {
          int row = bm + wave * 32 + mi * 16 + quad * 4 + r;
          ((float*)O0)[(size_t)row * 1024 + colg] = acc[mi][ni][r];
        }
      }
  } else {
    const int tile = blockIdx.x;
    if (tile < 16) {
      float gain = (tile < 8) ? q_gain[tile] * 0.125f : 1.f;
      float inv0 = exp2f(-13.287712379549449f * (float)l16 * (1.f / 32.f));
      float inv1 = exp2f(-13.287712379549449f * (float)(l16 + 16) * (1.f / 32.f));
#pragma unroll
      for (int mi = 0; mi < 2; ++mi) {
        int row0 = bm + wave * 32 + mi * 16 + quad * 4;
        if (row0 >= kMEXT) continue;          // 4-row group fully pad
        int b = row0 >= kTEXT ? 1 : 0;
        int te0 = row0 - b * kTEXT;
        if (tile < 12) {
          float ss[4];
#pragma unroll
          for (int r = 0; r < 4; ++r) {
            float s = 0.f;
#pragma unroll
            for (int ni = 0; ni < 4; ++ni) s += acc[mi][ni][r] * acc[mi][ni][r];
#pragma unroll
            for (int off = 1; off < 16; off <<= 1) s += __shfl_xor(s, off, 64);
            ss[r] = s;
          }
          bf16* base = (tile < 8)
            ? (bf16*)O0 + (((size_t)(b * 8 + tile)) * kTP + te0) * 64 + l16
            : (bf16*)O1 + (((size_t)(b * 4 + tile - 8)) * kTP + te0) * 64 + l16;
#pragma unroll
          for (int r = 0; r < 4; ++r) {
            float rn = rsqrtf(ss[r] * (1.f / 64.f) + 1e-6f) * gain;
            float te = (float)(te0 + r);
            float a0 = te * inv0, a1 = te * inv1;
            float c0 = __cosf(a0), s0 = __sinf(a0);
            float c1 = __cosf(a1), s1 = __sinf(a1);
            float v0 = acc[mi][0][r] * rn, v1 = acc[mi][1][r] * rn;
            float v2 = acc[mi][2][r] * rn, v3 = acc[mi][3][r] * rn;
            bf16* dst = base + (size_t)r * 64;
            dst[0]  = __float2bfloat16(v0 * c0 - v2 * s0);
            dst[16] = __float2bfloat16(v1 * c1 - v3 * s1);
            dst[32] = __float2bfloat16(v0 * s0 + v2 * c0);
            dst[48] = __float2bfloat16(v1 * s1 + v3 * c1);
          }
        } else {
          int hv = tile - 12;
#pragma unroll
          for (int ni = 0; ni < 4; ++ni) {
            union { unsigned long long q; bf16 hh[4]; } pw;
#pragma unroll
            for (int r = 0; r < 4; ++r) pw.hh[r] = __float2bfloat16(acc[mi][ni][r]);
            *(unsigned long long*)((bf16*)O2 +
                (((size_t)(b * 4 + hv)) * 64 + ni * 16 + l16) * kTP + te0) = pw.q;
          }
        }
      }
    } else {
      // ---- fused SSM prep: X (in acc) vs [dtw;Bw;Cw] of head hd ----
      const int hd = tile - 16;
      __syncthreads();   // all GEMM LDS reads done; smem reusable
      short (*Xl)[72] = (short(*)[72])smem;
      short (*Wl)[72] = (short(*)[72])(smem + 18432);
#pragma unroll
      for (int mi = 0; mi < 2; ++mi) {
        if (l16 == 0) {
#pragma unroll
          for (int r = 0; r < 4; ++r) {
            int row = bm + wave * 32 + mi * 16 + quad * 4 + r;
            if (row < kMEXT) {
              int bb = row >= kTEXT ? 1 : 0;
              int te = row - bb * kTEXT;
              if (te >= kNMETA) X0[(size_t)(bb * kT + te - kNMETA) * 8 + hd] = acc[mi][0][r];
            }
          }
        }
      }
#pragma unroll
      for (int mi = 0; mi < 2; ++mi)
#pragma unroll
        for (int ni = 0; ni < 4; ++ni)
#pragma unroll
          for (int r = 0; r < 4; ++r)
            Xl[wave * 32 + mi * 16 + quad * 4 + r][ni * 16 + l16] = bf2s(acc[mi][ni][r]);
      for (int s2 = tid; s2 < 384; s2 += 256) {
        int row = s2 >> 3, v = s2 & 7;
        const float* src = (row < 16) ? dtw + ((size_t)(hd * 16 + row)) * 64
                         : (row < 32) ? Bw + ((size_t)(hd * 16 + row - 16)) * 64
                                      : Cw + ((size_t)(hd * 16 + row - 32)) * 64;
        float4 a0 = ((const float4*)src)[v * 2];
        float4 a1 = ((const float4*)src)[v * 2 + 1];
        *(uint4*)&Wl[row][v * 8] = pack8(a0, a1);
      }
      __syncthreads();
      f32x4 a3[2][3] = {};
#pragma unroll
      for (int mt = 0; mt < 2; ++mt) {
        short8 xa0 = *(const short8*)&Xl[wave * 32 + mt * 16 + l16][quad * 8];
        short8 xa1 = *(const short8*)&Xl[wave * 32 + mt * 16 + l16][32 + quad * 8];
#pragma unroll
        for (int nb = 0; nb < 3; ++nb) {
          short8 wb0 = *(const short8*)&Wl[nb * 16 + l16][quad * 8];
          a3[mt][nb] = __builtin_amdgcn_mfma_f32_16x16x32_bf16(xa0, wb0, a3[mt][nb], 0, 0, 0);
          short8 wb1 = *(const short8*)&Wl[nb * 16 + l16][32 + quad * 8];
          a3[mt][nb] = __builtin_amdgcn_mfma_f32_16x16x32_bf16(xa1, wb1, a3[mt][nb], 0, 0, 0);
        }
      }
      float dtb_v = dtb[hd * 16 + l16];
      float A_v = fminf(-expf(logA[hd * 16 + l16]), 10.f);
#pragma unroll
      for (int mt = 0; mt < 2; ++mt)
#pragma unroll
        for (int r = 0; r < 4; ++r) {
          int row = bm + wave * 32 + mt * 16 + quad * 4 + r;
          if (row >= kMEXT) continue;
          int bb = row >= kTEXT ? 1 : 0;
          int te = row - bb * kTEXT;
          if (te < kNMETA) continue;
          size_t ix = (size_t)(bb * kT + te - kNMETA) * 128 + hd * 16 + l16;
          float raw = a3[mt][0][r] + dtb_v;
          float sp = fmaxf(raw, 0.f) + log1pf(expf(-fabsf(raw)));   // stable softplus
          float dt = fminf(sp, 1.f);
          float lav = fminf(fmaxf(dt * A_v, -0.5f), 0.f);
          *(float2*)(LU + 2 * ix) = make_float2(lav, a3[mt][1][r] * dt);
          CC[ix] = a3[mt][2][r];
        }
    }
  }
}

// ===== fused: SSM scan (blocks 0..63, dispatched first) + MFMA flash attention kv-split x3 =====
__global__ __launch_bounds__(256) void attn_scan(const bf16* __restrict__ Qp,
                                                 const bf16* __restrict__ Kp,
                                                 const bf16* __restrict__ Vt,
                                                 float* __restrict__ AO, float* __restrict__ AL,
                                                 const float* __restrict__ LU, bf16* __restrict__ HL) {
  __shared__ char sraw[27648];
  if (blockIdx.x < 64) {
    // ---------- SSM scan: 4 chains/block; pass1 local (H,P); wave scan; pass2 final h ----------
    float (*sH)[64] = (float(*)[64])sraw;
    float (*sP)[64] = (float(*)[64])(sraw + 1024);
    float (*sH0)[64] = (float(*)[64])(sraw + 2048);
    const int tid = threadIdx.x;
    const int ch = tid & 3, c = tid >> 2;
    const int chain = blockIdx.x * 4 + ch;       // 0..255
    const int b = chain >> 7, hs = chain & 127;
    const float2* LU2 = (const float2*)LU;
    const size_t base = ((size_t)b * kT) * 128 + hs;
    float H = 0.f, cum = 0.f;
    for (int i = 0; i < 32; ++i) {
      float2 lu = LU2[base + (size_t)(c * 32 + i) * 128];
      cum += lu.x;
      H = __expf(lu.x) * H + lu.y;
    }
    sH[ch][c] = H;
    sP[ch][c] = __expf(cum);       // cum >= -16, no clip needed
    __syncthreads();
    const int wv = tid >> 6, lane = tid & 63;
    float Hs = sH[wv][lane], Ps = sP[wv][lane];
#pragma unroll
    for (int off = 1; off < 64; off <<= 1) {
      float Hp = __shfl_up(Hs, off, 64);
      float Pp = __shfl_up(Ps, off, 64);
      if (lane >= off) { Hs = Hs + Ps * Hp; Ps = Ps * Pp; }
    }
    float Hex = __shfl_up(Hs, 1, 64);
    if (lane == 0) Hex = 0.f;
    sH0[wv][lane] = Hex;
    __syncthreads();
    float h = sH0[ch][c];          // exclusive prefix = h entering this sub-chunk
    for (int i = 0; i < 32; ++i) {
      size_t ix = base + (size_t)(c * 32 + i) * 128;
      float2 lu = LU2[ix];
      h = __expf(lu.x) * h + lu.y;
      HL[ix] = __float2bfloat16(h);
    }
    return;
  }
  // ---------- attention ----------
  short (*Ks)[72] = (short(*)[72])sraw;
  short (*Vs)[72] = (short(*)[72])(sraw + 9216);
  short (*Ps)[16][72] = (short(*)[16][72])(sraw + 18432);
  const int i = blockIdx.x - 64;              // 0..1583 : x = i%99, h = (i/99)%8, b = i/792
  const int xq = i % 99;
  const int h = (i / 99) & 7, b = i / 792;
  const int part = xq % 3;
  const int qt = (kQT - 1) - (xq / 3);        // longest first
  const int kvh = h >> 1;
  const int tid = threadIdx.x, wave = tid >> 6, lane = tid & 63;
  const int quad = lane >> 4, l16 = lane & 15;
  const int ntiles = qt + 1;
  const int s1 = ntiles / 3, s2 = (2 * ntiles) / 3;
  const int kt_begin = (part == 0) ? 0 : (part == 1 ? s1 : s2);
  const int kt_end = (part == 0) ? s1 : (part == 1 ? s2 : ntiles);   // exclusive
  const int kt_pf = (kt_begin < kt_end) ? kt_begin : 0;              // clamp for empty ranges

  short8 qf[2];
  {
    const bf16* qrow = Qp + (((size_t)(b * 8 + h)) * kTP + qt * 64 + wave * 16 + l16) * 64 + quad * 8;
    qf[0] = *(const short8*)(qrow);
    qf[1] = *(const short8*)(qrow + 32);
  }
  short8 ones;
#pragma unroll
  for (int j = 0; j < 8; ++j) ones[j] = (short)0x3F80;   // bf16 1.0

  const bf16* kbase = Kp + ((size_t)(b * 4 + kvh)) * kTP * 64;
  const bf16* vbase = Vt + ((size_t)(b * 4 + kvh)) * 64 * kTP;

  const int r0row = tid >> 3, r0c8 = tid & 7;
  const int r1row = (256 + tid) >> 3, r1c8 = tid & 7;

  f32x4 O[4] = {};
  f32x4 lacc = {};
  const int q_abs = qt * 64 + wave * 16 + l16;

  uint4 kr0 = *(const uint4*)(kbase + (size_t)(kt_pf * 64 + r0row) * 64 + r0c8 * 8);
  uint4 kr1 = *(const uint4*)(kbase + (size_t)(kt_pf * 64 + r1row) * 64 + r1c8 * 8);
  uint4 vr0 = *(const uint4*)(vbase + (size_t)r0row * kTP + kt_pf * 64 + r0c8 * 8);
  uint4 vr1 = *(const uint4*)(vbase + (size_t)r1row * kTP + kt_pf * 64 + r1c8 * 8);

  for (int kt = kt_begin; kt < kt_end; ++kt) {
    __syncthreads();
    *(uint4*)&Ks[r0row][r0c8 * 8] = kr0;
    *(uint4*)&Ks[r1row][r1c8 * 8] = kr1;
    *(uint4*)&Vs[r0row][r0c8 * 8] = vr0;
    *(uint4*)&Vs[r1row][r1c8 * 8] = vr1;
    if (kt + 1 < kt_end) {
      int kn = (kt + 1) * 64;
      kr0 = *(const uint4*)(kbase + (size_t)(kn + r0row) * 64 + r0c8 * 8);
      kr1 = *(const uint4*)(kbase + (size_t)(kn + r1row) * 64 + r1c8 * 8);
      vr0 = *(const uint4*)(vbase + (size_t)r0row * kTP + kn + r0c8 * 8);
      vr1 = *(const uint4*)(vbase + (size_t)r1row * kTP + kn + r1c8 * 8);
    }
    __syncthreads();

    f32x4 st[4] = {};
#pragma unroll
    for (int nb = 0; nb < 4; ++nb) {
      short8 ak0 = *(const short8*)&Ks[nb * 16 + l16][quad * 8];
      st[nb] = __builtin_amdgcn_mfma_f32_16x16x32_bf16(ak0, qf[0], st[nb], 0, 0, 0);
      short8 ak1 = *(const short8*)&Ks[nb * 16 + l16][32 + quad * 8];
      st[nb] = __builtin_amdgcn_mfma_f32_16x16x32_bf16(ak1, qf[1], st[nb], 0, 0, 0);
    }
    if (kt == qt) {
      int key0 = kt * 64 + quad * 4;
#pragma unroll
      for (int nb = 0; nb < 4; ++nb)
#pragma unroll
        for (int rg = 0; rg < 4; ++rg)
          if (key0 + nb * 16 + rg > q_abs) st[nb][rg] = -1e30f;
    }
#pragma unroll
    for (int nb = 0; nb < 4; ++nb) {
      union { unsigned long long q; bf16 hh[4]; } pw;
#pragma unroll
      for (int rg = 0; rg < 4; ++rg) pw.hh[rg] = __float2bfloat16(__expf(st[nb][rg]));
      *(unsigned long long*)&Ps[wave][l16][nb * 16 + quad * 4] = pw.q;
    }
    short8 pf0 = *(const short8*)&Ps[wave][l16][quad * 8];
    short8 pf1 = *(const short8*)&Ps[wave][l16][32 + quad * 8];
    lacc = __builtin_amdgcn_mfma_f32_16x16x32_bf16(pf0, ones, lacc, 0, 0, 0);
    lacc = __builtin_amdgcn_mfma_f32_16x16x32_bf16(pf1, ones, lacc, 0, 0, 0);
#pragma unroll
    for (int db = 0; db < 4; ++db) {
      short8 bv0 = *(const short8*)&Vs[db * 16 + l16][quad * 8];
      O[db] = __builtin_amdgcn_mfma_f32_16x16x32_bf16(pf0, bv0, O[db], 0, 0, 0);
      short8 bv1 = *(const short8*)&Vs[db * 16 + l16][32 + quad * 8];
      O[db] = __builtin_amdgcn_mfma_f32_16x16x32_bf16(pf1, bv1, O[db], 0, 0, 0);
    }
  }
  size_t hb = (((size_t)part * 2 + b) * 8 + h);
  float* aoB = AO + hb * kTP * 64;
  float* alB = AL + hb * kTP;
#pragma unroll
  for (int rg = 0; rg < 4; ++rg) {
    int q = qt * 64 + wave * 16 + quad * 4 + rg;
    float* dst = aoB + (size_t)q * 64 + l16;
#pragma unroll
    for (int db = 0; db < 4; ++db) dst[db * 16] = O[db][rg];
    if (l16 == 0) alB[q] = lacc[rg];
  }
}

// ------- fused: attn kv-split combine (blocks 0..527) + ssm output (blocks 528..1039) -------
__global__ __launch_bounds__(256) void combine_out(const float* __restrict__ AO,
                                                   const float* __restrict__ AL,
                                                   const float* __restrict__ attn_scale,
                                                   const bf16* __restrict__ HL, const float* __restrict__ CC,
                                                   const float* __restrict__ X0, const float* __restrict__ Ow,
                                                   const float* __restrict__ ssm_scale,
                                                   bf16* __restrict__ Y) {
  if (blockIdx.x < 528) {
    int id = blockIdx.x * 256 + threadIdx.x;     // 2*8*2112*4
    int d16 = id & 3;
    int tmp = id >> 2;
    int q = tmp % kTP; tmp /= kTP;
    int h = tmp & 7, b = tmp >> 3;
    if (q < kNMETA || q >= kTEXT) return;
    size_t hb0 = ((size_t)b * 8 + h), hb1 = ((size_t)(2 + b) * 8 + h), hb2 = ((size_t)(4 + b) * 8 + h);
    float l = AL[hb0 * kTP + q] + AL[hb1 * kTP + q] + AL[hb2 * kTP + q];
    float so = attn_scale[0] / fmaxf(l, 1e-30f);
    const float4* p0 = (const float4*)(AO + (hb0 * kTP + q) * 64 + d16 * 16);
    const float4* p1 = (const float4*)(AO + (hb1 * kTP + q) * 64 + d16 * 16);
    const float4* p2 = (const float4*)(AO + (hb2 * kTP + q) * 64 + d16 * 16);
    bf16* dst = Y + ((size_t)(b * kT + q - kNMETA)) * kDIM + h * 64 + d16 * 16;
#pragma unroll
    for (int j = 0; j < 4; ++j) {
      float4 a = p0[j], c = p1[j], e = p2[j];
      dst[j * 4 + 0] = __float2bfloat16((a.x + c.x + e.x) * so);
      dst[j * 4 + 1] = __float2bfloat16((a.y + c.y + e.y) * so);
      dst[j * 4 + 2] = __float2bfloat16((a.z + c.z + e.z) * so);
      dst[j * 4 + 3] = __float2bfloat16((a.w + c.w + e.w) * so);
    }
  } else {
    int id = (blockIdx.x - 528) * 256 + threadIdx.x;   // kMX*32
    int d4 = id & 3, h = (id >> 2) & 7, t = (id >> 5) & 2047, b = id >> 16;
    size_t ix0 = ((size_t)(b * kT + t)) * 128 + h * 16;
    float hv[16], y = 0.f;
#pragma unroll
    for (int s = 0; s < 16; ++s) {
      float v = __bfloat162float(HL[ix0 + s]);
      hv[s] = v;
      y += CC[ix0 + s] * v;
    }
    float x0 = X0[(size_t)(b * kT + t) * 8 + h];
    float scl = ssm_scale[0];
    const float* ow = Ow + ((size_t)h * 64 + d4 * 16) * 16;
    bf16* dst = Y + ((size_t)(b * kT + t)) * kDIM + 512 + h * 64 + d4 * 16;
    float yx = y * x0;
#pragma unroll
    for (int d = 0; d < 16; ++d) {
      float acc = yx;
      const float* owr = ow + d * 16;
#pragma unroll
      for (int s = 0; s < 16; ++s) acc += hv[s] * owr[s];
      dst[d] = __float2bfloat16(acc * scl);
    }
  }
}

// ---------------- host ----------------
extern "C" void kernel_launch(void* const* d_in, const int* in_sizes, int n_in,
                              void* d_out, int out_size, void* d_ws, size_t ws_size,
                              hipStream_t stream) {
  (void)in_sizes; (void)n_in; (void)out_size; (void)ws_size;
  const float* x        = (const float*)d_in[0];
  const float* meta     = (const float*)d_in[1];
  const float* c_q_w    = (const float*)d_in[2];
  const float* c_k_w    = (const float*)d_in[3];
  const float* c_v_w    = (const float*)d_in[4];
  const float* q_gain   = (const float*)d_in[5];
  const float* ssm_in_w = (const float*)d_in[6];
  const float* proj_w   = (const float*)d_in[7];
  const float* attn_sc  = (const float*)d_in[8];
  const float* ssm_sc   = (const float*)d_in[9];
  const float* ssm_logA = (const float*)d_in[10];
  const float* ssm_Bw   = (const float*)d_in[11];
  const float* ssm_Cw   = (const float*)d_in[12];
  const float* ssm_dtw  = (const float*)d_in[13];
  const float* ssm_dtb  = (const float*)d_in[14];
  const float* ssm_Ow   = (const float*)d_in[15];

  char* w = (char*)d_ws;
  bf16*  XE = (bf16*)(w + oXE);
  bf16*  YB = (bf16*)(w + oYB);
  bf16*  QP = (bf16*)(w + oQP);
  bf16*  KP = (bf16*)(w + oKP);
  bf16*  VT = (bf16*)(w + oVT);
  bf16*  WQ = (bf16*)(w + oWQ);
  bf16*  WP = (bf16*)(w + oWP);
  float* LU = (float*)(w + oLU);
  float* CC = (float*)(w + oCC);
  bf16*  HL = (bf16*)(w + oHL);
  float* X0 = (float*)(w + oX0);
  float* AO = (float*)(w + oAO);
  float* AL = (float*)(w + oAL);

  prep_all<<<3632, 256, 0, stream>>>(c_q_w, c_k_w, c_v_w, ssm_in_w, proj_w,
                                     x, meta, WQ, WP, XE, QP, KP, VT);

  // QKV + SSM-prep fused GEMM
  gemm_t<0><<<dim3(24, kMPAD / 128), 256, 0, stream>>>(XE, WQ, QP, KP, VT, q_gain,
                                                       ssm_dtw, ssm_dtb, ssm_Bw, ssm_Cw,
                                                       ssm_logA, LU, CC, X0);

  // scan (blocks 0..63) + attention kv-split x3 (blocks 64..1647)
  attn_scan<<<64 + kQT * 3 * 8 * kB, 256, 0, stream>>>(QP, KP, VT, AO, AL, LU, HL);

  combine_out<<<1040, 256, 0, stream>>>(AO, AL, attn_sc, HL, CC, X0, ssm_Ow, ssm_sc, YB);

  gemm_t<2><<<dim3(16, kMX / 128), 256, 0, stream>>>(YB, WP, d_out, nullptr, nullptr, nullptr,
                                                     nullptr, nullptr, nullptr, nullptr, nullptr,
                                                     nullptr, nullptr, nullptr);
}

// Round 15
// 194.359 us; speedup vs baseline: 1.1674x; 1.0197x over previous
//
#include <hip/hip_runtime.h>
#include <hip/hip_bf16.h>
#include <math.h>

typedef __hip_bfloat16 bf16;
typedef __attribute__((ext_vector_type(8))) short short8;   // 8 bf16 = 4 VGPRs (MFMA A/B frag)
typedef __attribute__((ext_vector_type(4))) float f32x4;    // MFMA C/D frag

static constexpr int kB = 2;
static constexpr int kT = 2048;
static constexpr int kDIM = 1024;
static constexpr int kNMETA = 4;
static constexpr int kTEXT = kT + kNMETA;   // 2052
static constexpr int kMEXT = kB * kTEXT;    // 4104
static constexpr int kMPAD = 4224;          // 33*128
static constexpr int kMX = kB * kT;         // 4096
static constexpr int kQT = 33;
static constexpr int kTP = 2112;            // 33*64

// ---------- workspace layout (bytes); ws ~268 MB ----------
static constexpr size_t oXE = 0;                                  // x_ext bf16 [4224][1024]
static constexpr size_t oYB = 0;                                  // aliases XE (dead after GEMMs)
static constexpr size_t oLU = 8650752;                            // la/u interleaved f32x2 [4096][128]
static constexpr size_t oCC = oLU + (size_t)kMX * 128 * 8;        // Cc f32 [4096][128]
static constexpr size_t oHL = oCC + (size_t)kMX * 128 * 4;        // final h bf16 [4096][128]
static constexpr size_t oX0 = oHL + (size_t)kMX * 128 * 2;        // x0 f32 [4096][8]
static constexpr size_t oQP = oX0 + (size_t)kMX * 8 * 4;          // Qp bf16 [b][8][2112][64]
static constexpr size_t oKP = oQP + (size_t)kB * 8 * kTP * 64 * 2;// Kp bf16 [b][4][2112][64]
static constexpr size_t oVT = oKP + (size_t)kB * 4 * kTP * 64 * 2;// Vt bf16 [b][4][64][2112]
static constexpr size_t oWP = oVT + (size_t)kB * 4 * 64 * kTP * 2;// Wproj bf16 [1024][1024]
static constexpr size_t oWQ = oWP + (size_t)1024 * 1024 * 2;      // WQKV+WSX bf16 [1536][1024]
static constexpr size_t oAO = 134217728;                          // attn partial O bf16 [3][b][8][2112][64]
static constexpr size_t oAL = oAO + (size_t)3 * kB * 8 * kTP * 64 * 2;  // partial l f32 [3][b][8][2112]

#define GLD_LDS16(gp, lp)                                                          \
  __builtin_amdgcn_global_load_lds((const __attribute__((address_space(1))) void*)(gp), \
                                   (__attribute__((address_space(3))) void*)(lp), 16, 0, 0)

__device__ __forceinline__ short bf2s(float f) {
  union { bf16 h; short s; } u;
  u.h = __float2bfloat16(f);
  return u.s;
}

__device__ __forceinline__ float bf2f(unsigned short u) {
  return __uint_as_float(((unsigned int)u) << 16);
}

__device__ __forceinline__ uint4 pack8(float4 a, float4 b) {
  union { bf16 h[8]; uint4 v; } u;
  u.h[0] = __float2bfloat16(a.x); u.h[1] = __float2bfloat16(a.y);
  u.h[2] = __float2bfloat16(a.z); u.h[3] = __float2bfloat16(a.w);
  u.h[4] = __float2bfloat16(b.x); u.h[5] = __float2bfloat16(b.y);
  u.h[6] = __float2bfloat16(b.z); u.h[7] = __float2bfloat16(b.w);
  return u.v;
}

// accumulate 16 bf16 into f32[16]
__device__ __forceinline__ void add16bf(const bf16* p, float* o) {
  uint4 a = ((const uint4*)p)[0], b = ((const uint4*)p)[1];
  const unsigned short* s0 = (const unsigned short*)&a;
  const unsigned short* s1 = (const unsigned short*)&b;
#pragma unroll
  for (int i = 0; i < 8; ++i) { o[i] += bf2f(s0[i]); o[8 + i] += bf2f(s1[i]); }
}

// ---- prep: weight converts + x_ext build + QP/KP/VT tail zeroing, one launch ----
__global__ __launch_bounds__(256) void prep_all(const float* __restrict__ cq, const float* __restrict__ ck,
                                                const float* __restrict__ cv, const float* __restrict__ sw,
                                                const float* __restrict__ pw,
                                                const float* __restrict__ x, const float* __restrict__ meta,
                                                bf16* __restrict__ wqkvsx, bf16* __restrict__ wproj,
                                                bf16* __restrict__ xe,
                                                bf16* __restrict__ Qp, bf16* __restrict__ Kp,
                                                bf16* __restrict__ Vt) {
  int i = blockIdx.x * 256 + threadIdx.x;
  if (i < 327680) {                       // seg0: weights
    int row = i >> 7, v = i & 127;
    const float* src; bf16* dst;
    if (row < 512)       { src = cq + (size_t)row * 1024;          dst = wqkvsx + (size_t)row * 1024; }
    else if (row < 768)  { src = ck + (size_t)(row - 512) * 1024;  dst = wqkvsx + (size_t)row * 1024; }
    else if (row < 1024) { src = cv + (size_t)(row - 768) * 1024;  dst = wqkvsx + (size_t)row * 1024; }
    else if (row < 1536) { src = sw + (size_t)(row - 1024) * 1024; dst = wqkvsx + (size_t)row * 1024; }
    else                 { src = pw + (size_t)(row - 1536) * 1024; dst = wproj + (size_t)(row - 1536) * 1024; }
    float4 a0 = ((const float4*)src)[v * 2], a1 = ((const float4*)src)[v * 2 + 1];
    ((uint4*)dst)[v] = pack8(a0, a1);
  } else if (i < 868352) {                // seg1: x_ext
    int j = i - 327680;
    int r = j >> 7, v = j & 127;
    uint4 val = {0u, 0u, 0u, 0u};
    if (r < kMEXT) {
      int b = r / kTEXT, te = r - b * kTEXT;
      const float* src = (te < kNMETA) ? (meta + (size_t)te * kDIM)
                                       : (x + ((size_t)b * kT + (te - kNMETA)) * kDIM);
      float4 a0 = ((const float4*)src)[v * 2];
      float4 a1 = ((const float4*)src)[v * 2 + 1];
      val = pack8(a0, a1);
    }
    ((uint4*)(xe + (size_t)r * kDIM))[v] = val;
  } else {                                // seg2: zero pad tails (uint = 2 bf16)
    int j = i - 868352;
    if (j < 30720) {            // QP tails
      int k = j & 31, te = (j >> 5) % 60, bh = j / (60 * 32);
      *(unsigned int*)(Qp + ((size_t)bh * kTP + 2052 + te) * 64 + k * 2) = 0u;
    } else if (j < 46080) {     // KP tails
      int jj = j - 30720;
      int k = jj & 31, te = (jj >> 5) % 60, bh = jj / (60 * 32);
      *(unsigned int*)(Kp + ((size_t)bh * kTP + 2052 + te) * 64 + k * 2) = 0u;
    } else if (j < 61440) {     // VT tails
      int jj = j - 46080;
      int k = jj % 30, rowd = jj / 30;
      *(unsigned int*)(Vt + (size_t)rowd * kTP + 2052 + k * 2) = 0u;
    }
  }
}

// ========== 128x64-tile bf16 GEMM, BK=64 (2 panels), DOUBLE-BUFFERED GLD, 1 barrier/iter ====
template <int MODE>
__global__ __launch_bounds__(256) void gemm_t(const bf16* __restrict__ A,
                                              const bf16* __restrict__ W,
                                              void* __restrict__ O0, void* __restrict__ O1,
                                              void* __restrict__ O2,
                                              const float* __restrict__ q_gain,
                                              const float* __restrict__ dtw, const float* __restrict__ dtb,
                                              const float* __restrict__ Bw, const float* __restrict__ Cw,
                                              const float* __restrict__ logA,
                                              float* __restrict__ LU, float* __restrict__ CC,
                                              float* __restrict__ X0) {
  __shared__ char smem[49152];             // 2 x 24 KB; MODE0 epilogue overlay (25.3 KB) fits
  const int tid = threadIdx.x;
  const int wave = tid >> 6, lane = tid & 63;
  const int quad = lane >> 4, l16 = lane & 15;
  const int bm = blockIdx.y * 128, bn = blockIdx.x * 64;
  const bf16* ag0 = A + (size_t)(bm + (tid >> 2)) * 1024 + (tid & 3) * 8;        // rows 0..63
  const bf16* ag1 = A + (size_t)(bm + 64 + (tid >> 2)) * 1024 + (tid & 3) * 8;   // rows 64..127
  const bf16* bg0 = W + (size_t)(bn + (tid >> 2)) * 1024 + (tid & 3) * 8;
  f32x4 acc[2][4] = {};
  {  // prefetch iter 0 into buf0
    char* sb = smem + wave * 1024;
    GLD_LDS16(ag0, sb);
    GLD_LDS16(ag1, sb + 4096);
    GLD_LDS16(ag0 + 32, sb + 8192);
    GLD_LDS16(ag1 + 32, sb + 12288);
    GLD_LDS16(bg0, sb + 16384);
    GLD_LDS16(bg0 + 32, sb + 20480);
    ag0 += 64; ag1 += 64; bg0 += 64;
  }
  for (int k = 0; k < 16; ++k) {
    char* cur = smem + (k & 1) * 24576;
    char* nxt = smem + ((k & 1) ^ 1) * 24576;
    __syncthreads();                       // cur's loads landed (in flight a full iter)
    if (k < 15) {                          // issue next tile into the other buffer
      char* sb = nxt + wave * 1024;
      GLD_LDS16(ag0, sb);
      GLD_LDS16(ag1, sb + 4096);
      GLD_LDS16(ag0 + 32, sb + 8192);
      GLD_LDS16(ag1 + 32, sb + 12288);
      GLD_LDS16(bg0, sb + 16384);
      GLD_LDS16(bg0 + 32, sb + 20480);
      ag0 += 64; ag1 += 64; bg0 += 64;
    }
#pragma unroll
    for (int p = 0; p < 2; ++p) {
      short8 af[2], bfr[4];
#pragma unroll
      for (int mi = 0; mi < 2; ++mi)
        af[mi] = *(const short8*)(cur + p * 8192 +
                                  (size_t)(wave * 32 + mi * 16 + l16) * 64 + quad * 16);
#pragma unroll
      for (int ni = 0; ni < 4; ++ni)
        bfr[ni] = *(const short8*)(cur + 16384 + p * 4096 +
                                   (size_t)(ni * 16 + l16) * 64 + quad * 16);
#pragma unroll
      for (int mi = 0; mi < 2; ++mi)
#pragma unroll
        for (int ni = 0; ni < 4; ++ni)
          acc[mi][ni] = __builtin_amdgcn_mfma_f32_16x16x32_bf16(af[mi], bfr[ni], acc[mi][ni], 0, 0, 0);
    }
  }
  // ---- epilogue ----
  if constexpr (MODE == 2) {
#pragma unroll
    for (int mi = 0; mi < 2; ++mi)
#pragma unroll
      for (int ni = 0; ni < 4; ++ni) {
        int colg = bn + ni * 16 + l16;
#pragma unroll
        for (int r = 0; r < 4; ++r) {
          int row = bm + wave * 32 + mi * 16 + quad * 4 + r;
          ((float*)O0)[(size_t)row * 1024 + colg] = acc[mi][ni][r];
        }
      }
  } else {
    const int tile = blockIdx.x;
    if (tile < 16) {
      float gain = (tile < 8) ? q_gain[tile] * 0.125f : 1.f;
      float inv0 = exp2f(-13.287712379549449f * (float)l16 * (1.f / 32.f));
      float inv1 = exp2f(-13.287712379549449f * (float)(l16 + 16) * (1.f / 32.f));
#pragma unroll
      for (int mi = 0; mi < 2; ++mi) {
        int row0 = bm + wave * 32 + mi * 16 + quad * 4;
        if (row0 >= kMEXT) continue;          // 4-row group fully pad
        int b = row0 >= kTEXT ? 1 : 0;
        int te0 = row0 - b * kTEXT;
        if (tile < 12) {
          float ss[4];
#pragma unroll
          for (int r = 0; r < 4; ++r) {
            float s = 0.f;
#pragma unroll
            for (int ni = 0; ni < 4; ++ni) s += acc[mi][ni][r] * acc[mi][ni][r];
#pragma unroll
            for (int off = 1; off < 16; off <<= 1) s += __shfl_xor(s, off, 64);
            ss[r] = s;
          }
          bf16* base = (tile < 8)
            ? (bf16*)O0 + (((size_t)(b * 8 + tile)) * kTP + te0) * 64 + l16
            : (bf16*)O1 + (((size_t)(b * 4 + tile - 8)) * kTP + te0) * 64 + l16;
#pragma unroll
          for (int r = 0; r < 4; ++r) {
            float rn = rsqrtf(ss[r] * (1.f / 64.f) + 1e-6f) * gain;
            float te = (float)(te0 + r);
            float a0 = te * inv0, a1 = te * inv1;
            float c0 = __cosf(a0), s0 = __sinf(a0);
            float c1 = __cosf(a1), s1 = __sinf(a1);
            float v0 = acc[mi][0][r] * rn, v1 = acc[mi][1][r] * rn;
            float v2 = acc[mi][2][r] * rn, v3 = acc[mi][3][r] * rn;
            bf16* dst = base + (size_t)r * 64;
            dst[0]  = __float2bfloat16(v0 * c0 - v2 * s0);
            dst[16] = __float2bfloat16(v1 * c1 - v3 * s1);
            dst[32] = __float2bfloat16(v0 * s0 + v2 * c0);
            dst[48] = __float2bfloat16(v1 * s1 + v3 * c1);
          }
        } else {
          int hv = tile - 12;
#pragma unroll
          for (int ni = 0; ni < 4; ++ni) {
            union { unsigned long long q; bf16 hh[4]; } pw;
#pragma unroll
            for (int r = 0; r < 4; ++r) pw.hh[r] = __float2bfloat16(acc[mi][ni][r]);
            *(unsigned long long*)((bf16*)O2 +
                (((size_t)(b * 4 + hv)) * 64 + ni * 16 + l16) * kTP + te0) = pw.q;
          }
        }
      }
    } else {
      // ---- fused SSM prep: X (in acc) vs [dtw;Bw;Cw] of head hd ----
      const int hd = tile - 16;
      __syncthreads();   // all GEMM LDS reads done; smem reusable
      short (*Xl)[72] = (short(*)[72])smem;
      short (*Wl)[72] = (short(*)[72])(smem + 18432);
#pragma unroll
      for (int mi = 0; mi < 2; ++mi) {
        if (l16 == 0) {
#pragma unroll
          for (int r = 0; r < 4; ++r) {
            int row = bm + wave * 32 + mi * 16 + quad * 4 + r;
            if (row < kMEXT) {
              int bb = row >= kTEXT ? 1 : 0;
              int te = row - bb * kTEXT;
              if (te >= kNMETA) X0[(size_t)(bb * kT + te - kNMETA) * 8 + hd] = acc[mi][0][r];
            }
          }
        }
      }
#pragma unroll
      for (int mi = 0; mi < 2; ++mi)
#pragma unroll
        for (int ni = 0; ni < 4; ++ni)
#pragma unroll
          for (int r = 0; r < 4; ++r)
            Xl[wave * 32 + mi * 16 + quad * 4 + r][ni * 16 + l16] = bf2s(acc[mi][ni][r]);
      for (int s2 = tid; s2 < 384; s2 += 256) {
        int row = s2 >> 3, v = s2 & 7;
        const float* src = (row < 16) ? dtw + ((size_t)(hd * 16 + row)) * 64
                         : (row < 32) ? Bw + ((size_t)(hd * 16 + row - 16)) * 64
                                      : Cw + ((size_t)(hd * 16 + row - 32)) * 64;
        float4 a0 = ((const float4*)src)[v * 2];
        float4 a1 = ((const float4*)src)[v * 2 + 1];
        *(uint4*)&Wl[row][v * 8] = pack8(a0, a1);
      }
      __syncthreads();
      f32x4 a3[2][3] = {};
#pragma unroll
      for (int mt = 0; mt < 2; ++mt) {
        short8 xa0 = *(const short8*)&Xl[wave * 32 + mt * 16 + l16][quad * 8];
        short8 xa1 = *(const short8*)&Xl[wave * 32 + mt * 16 + l16][32 + quad * 8];
#pragma unroll
        for (int nb = 0; nb < 3; ++nb) {
          short8 wb0 = *(const short8*)&Wl[nb * 16 + l16][quad * 8];
          a3[mt][nb] = __builtin_amdgcn_mfma_f32_16x16x32_bf16(xa0, wb0, a3[mt][nb], 0, 0, 0);
          short8 wb1 = *(const short8*)&Wl[nb * 16 + l16][32 + quad * 8];
          a3[mt][nb] = __builtin_amdgcn_mfma_f32_16x16x32_bf16(xa1, wb1, a3[mt][nb], 0, 0, 0);
        }
      }
      float dtb_v = dtb[hd * 16 + l16];
      float A_v = fminf(-expf(logA[hd * 16 + l16]), 10.f);
#pragma unroll
      for (int mt = 0; mt < 2; ++mt)
#pragma unroll
        for (int r = 0; r < 4; ++r) {
          int row = bm + wave * 32 + mt * 16 + quad * 4 + r;
          if (row >= kMEXT) continue;
          int bb = row >= kTEXT ? 1 : 0;
          int te = row - bb * kTEXT;
          if (te < kNMETA) continue;
          size_t ix = (size_t)(bb * kT + te - kNMETA) * 128 + hd * 16 + l16;
          float raw = a3[mt][0][r] + dtb_v;
          float sp = fmaxf(raw, 0.f) + log1pf(expf(-fabsf(raw)));   // stable softplus
          float dt = fminf(sp, 1.f);
          float lav = fminf(fmaxf(dt * A_v, -0.5f), 0.f);
          *(float2*)(LU + 2 * ix) = make_float2(lav, a3[mt][1][r] * dt);
          CC[ix] = a3[mt][2][r];
        }
    }
  }
}

// ===== fused: SSM scan (blocks 0..63) + MFMA flash attention kv-split x3 (bf16 partials) =====
__global__ __launch_bounds__(256) void attn_scan(const bf16* __restrict__ Qp,
                                                 const bf16* __restrict__ Kp,
                                                 const bf16* __restrict__ Vt,
                                                 bf16* __restrict__ AO, float* __restrict__ AL,
                                                 const float* __restrict__ LU, bf16* __restrict__ HL) {
  __shared__ char sraw[27648];
  if (blockIdx.x < 64) {
    float (*sH)[64] = (float(*)[64])sraw;
    float (*sP)[64] = (float(*)[64])(sraw + 1024);
    float (*sH0)[64] = (float(*)[64])(sraw + 2048);
    const int tid = threadIdx.x;
    const int ch = tid & 3, c = tid >> 2;
    const int chain = blockIdx.x * 4 + ch;       // 0..255
    const int b = chain >> 7, hs = chain & 127;
    const float2* LU2 = (const float2*)LU;
    const size_t base = ((size_t)b * kT) * 128 + hs;
    float H = 0.f, cum = 0.f;
    for (int i = 0; i < 32; ++i) {
      float2 lu = LU2[base + (size_t)(c * 32 + i) * 128];
      cum += lu.x;
      H = __expf(lu.x) * H + lu.y;
    }
    sH[ch][c] = H;
    sP[ch][c] = __expf(cum);       // cum >= -16, no clip needed
    __syncthreads();
    const int wv = tid >> 6, lane = tid & 63;
    float Hs = sH[wv][lane], Ps = sP[wv][lane];
#pragma unroll
    for (int off = 1; off < 64; off <<= 1) {
      float Hp = __shfl_up(Hs, off, 64);
      float Pp = __shfl_up(Ps, off, 64);
      if (lane >= off) { Hs = Hs + Ps * Hp; Ps = Ps * Pp; }
    }
    float Hex = __shfl_up(Hs, 1, 64);
    if (lane == 0) Hex = 0.f;
    sH0[wv][lane] = Hex;
    __syncthreads();
    float h = sH0[ch][c];          // exclusive prefix = h entering this sub-chunk
    for (int i = 0; i < 32; ++i) {
      size_t ix = base + (size_t)(c * 32 + i) * 128;
      float2 lu = LU2[ix];
      h = __expf(lu.x) * h + lu.y;
      HL[ix] = __float2bfloat16(h);
    }
    return;
  }
  // ---------- attention ----------
  short (*Ks)[72] = (short(*)[72])sraw;
  short (*Vs)[72] = (short(*)[72])(sraw + 9216);
  short (*Ps)[16][72] = (short(*)[16][72])(sraw + 18432);
  const int i = blockIdx.x - 64;              // 0..1583 : x = i%99, h = (i/99)%8, b = i/792
  const int xq = i % 99;
  const int h = (i / 99) & 7, b = i / 792;
  const int part = xq % 3;
  const int qt = (kQT - 1) - (xq / 3);        // longest first
  const int kvh = h >> 1;
  const int tid = threadIdx.x, wave = tid >> 6, lane = tid & 63;
  const int quad = lane >> 4, l16 = lane & 15;
  const int ntiles = qt + 1;
  const int s1 = ntiles / 3, s2 = (2 * ntiles) / 3;
  const int kt_begin = (part == 0) ? 0 : (part == 1 ? s1 : s2);
  const int kt_end = (part == 0) ? s1 : (part == 1 ? s2 : ntiles);   // exclusive
  if (kt_begin >= kt_end) return;             // empty split: combine skips this part

  short8 qf[2];
  {
    const bf16* qrow = Qp + (((size_t)(b * 8 + h)) * kTP + qt * 64 + wave * 16 + l16) * 64 + quad * 8;
    qf[0] = *(const short8*)(qrow);
    qf[1] = *(const short8*)(qrow + 32);
  }
  short8 ones;
#pragma unroll
  for (int j = 0; j < 8; ++j) ones[j] = (short)0x3F80;   // bf16 1.0

  const bf16* kbase = Kp + ((size_t)(b * 4 + kvh)) * kTP * 64;
  const bf16* vbase = Vt + ((size_t)(b * 4 + kvh)) * 64 * kTP;

  const int r0row = tid >> 3, r0c8 = tid & 7;
  const int r1row = (256 + tid) >> 3, r1c8 = tid & 7;

  f32x4 O[4] = {};
  f32x4 lacc = {};
  const int q_abs = qt * 64 + wave * 16 + l16;

  uint4 kr0 = *(const uint4*)(kbase + (size_t)(kt_begin * 64 + r0row) * 64 + r0c8 * 8);
  uint4 kr1 = *(const uint4*)(kbase + (size_t)(kt_begin * 64 + r1row) * 64 + r1c8 * 8);
  uint4 vr0 = *(const uint4*)(vbase + (size_t)r0row * kTP + kt_begin * 64 + r0c8 * 8);
  uint4 vr1 = *(const uint4*)(vbase + (size_t)r1row * kTP + kt_begin * 64 + r1c8 * 8);

  for (int kt = kt_begin; kt < kt_end; ++kt) {
    __syncthreads();
    *(uint4*)&Ks[r0row][r0c8 * 8] = kr0;
    *(uint4*)&Ks[r1row][r1c8 * 8] = kr1;
    *(uint4*)&Vs[r0row][r0c8 * 8] = vr0;
    *(uint4*)&Vs[r1row][r1c8 * 8] = vr1;
    if (kt + 1 < kt_end) {
      int kn = (kt + 1) * 64;
      kr0 = *(const uint4*)(kbase + (size_t)(kn + r0row) * 64 + r0c8 * 8);
      kr1 = *(const uint4*)(kbase + (size_t)(kn + r1row) * 64 + r1c8 * 8);
      vr0 = *(const uint4*)(vbase + (size_t)r0row * kTP + kn + r0c8 * 8);
      vr1 = *(const uint4*)(vbase + (size_t)r1row * kTP + kn + r1c8 * 8);
    }
    __syncthreads();

    f32x4 st[4] = {};
#pragma unroll
    for (int nb = 0; nb < 4; ++nb) {
      short8 ak0 = *(const short8*)&Ks[nb * 16 + l16][quad * 8];
      st[nb] = __builtin_amdgcn_mfma_f32_16x16x32_bf16(ak0, qf[0], st[nb], 0, 0, 0);
      short8 ak1 = *(const short8*)&Ks[nb * 16 + l16][32 + quad * 8];
      st[nb] = __builtin_amdgcn_mfma_f32_16x16x32_bf16(ak1, qf[1], st[nb], 0, 0, 0);
    }
    if (kt == qt) {
      int key0 = kt * 64 + quad * 4;
#pragma unroll
      for (int nb = 0; nb < 4; ++nb)
#pragma unroll
        for (int rg = 0; rg < 4; ++rg)
          if (key0 + nb * 16 + rg > q_abs) st[nb][rg] = -1e30f;
    }
#pragma unroll
    for (int nb = 0; nb < 4; ++nb) {
      union { unsigned long long q; bf16 hh[4]; } pw;
#pragma unroll
      for (int rg = 0; rg < 4; ++rg) pw.hh[rg] = __float2bfloat16(__expf(st[nb][rg]));
      *(unsigned long long*)&Ps[wave][l16][nb * 16 + quad * 4] = pw.q;
    }
    short8 pf0 = *(const short8*)&Ps[wave][l16][quad * 8];
    short8 pf1 = *(const short8*)&Ps[wave][l16][32 + quad * 8];
    lacc = __builtin_amdgcn_mfma_f32_16x16x32_bf16(pf0, ones, lacc, 0, 0, 0);
    lacc = __builtin_amdgcn_mfma_f32_16x16x32_bf16(pf1, ones, lacc, 0, 0, 0);
#pragma unroll
    for (int db = 0; db < 4; ++db) {
      short8 bv0 = *(const short8*)&Vs[db * 16 + l16][quad * 8];
      O[db] = __builtin_amdgcn_mfma_f32_16x16x32_bf16(pf0, bv0, O[db], 0, 0, 0);
      short8 bv1 = *(const short8*)&Vs[db * 16 + l16][32 + quad * 8];
      O[db] = __builtin_amdgcn_mfma_f32_16x16x32_bf16(pf1, bv1, O[db], 0, 0, 0);
    }
  }
  size_t hb = (((size_t)part * 2 + b) * 8 + h);
  bf16* aoB = AO + hb * kTP * 64;
  float* alB = AL + hb * kTP;
#pragma unroll
  for (int rg = 0; rg < 4; ++rg) {
    int q = qt * 64 + wave * 16 + quad * 4 + rg;
    bf16* dst = aoB + (size_t)q * 64 + l16;
#pragma unroll
    for (int db = 0; db < 4; ++db) dst[db * 16] = __float2bfloat16(O[db][rg]);
    if (l16 == 0) alB[q] = lacc[rg];
  }
}

// ------- fused: attn kv-split combine (blocks 0..527) + ssm output (blocks 528..1039) -------
__global__ __launch_bounds__(256) void combine_out(const bf16* __restrict__ AO,
                                                   const float* __restrict__ AL,
                                                   const float* __restrict__ attn_scale,
                                                   const bf16* __restrict__ HL, const float* __restrict__ CC,
                                                   const float* __restrict__ X0, const float* __restrict__ Ow,
                                                   const float* __restrict__ ssm_scale,
                                                   bf16* __restrict__ Y) {
  if (blockIdx.x < 528) {
    int id = blockIdx.x * 256 + threadIdx.x;     // 2*8*2112*4
    int d16 = id & 3;
    int tmp = id >> 2;
    int q = tmp % kTP; tmp /= kTP;
    int h = tmp & 7, b = tmp >> 3;
    if (q < kNMETA || q >= kTEXT) return;
    int ntiles = (q >> 6) + 1;
    bool use0 = ntiles >= 3, use1 = ntiles >= 2;
    size_t hb0 = ((size_t)b * 8 + h), hb1 = ((size_t)(2 + b) * 8 + h), hb2 = ((size_t)(4 + b) * 8 + h);
    float l = (use0 ? AL[hb0 * kTP + q] : 0.f) + (use1 ? AL[hb1 * kTP + q] : 0.f) + AL[hb2 * kTP + q];
    float so = attn_scale[0] / fmaxf(l, 1e-30f);
    float ov[16];
#pragma unroll
    for (int j = 0; j < 16; ++j) ov[j] = 0.f;
    if (use0) add16bf(AO + (hb0 * kTP + q) * 64 + d16 * 16, ov);
    if (use1) add16bf(AO + (hb1 * kTP + q) * 64 + d16 * 16, ov);
    add16bf(AO + (hb2 * kTP + q) * 64 + d16 * 16, ov);
    bf16* dst = Y + ((size_t)(b * kT + q - kNMETA)) * kDIM + h * 64 + d16 * 16;
#pragma unroll
    for (int j = 0; j < 16; ++j) dst[j] = __float2bfloat16(ov[j] * so);
  } else {
    int id = (blockIdx.x - 528) * 256 + threadIdx.x;   // kMX*32
    int d4 = id & 3, h = (id >> 2) & 7, t = (id >> 5) & 2047, b = id >> 16;
    size_t ix0 = ((size_t)(b * kT + t)) * 128 + h * 16;
    float hv[16], y = 0.f;
#pragma unroll
    for (int s = 0; s < 16; ++s) {
      float v = __bfloat162float(HL[ix0 + s]);
      hv[s] = v;
      y += CC[ix0 + s] * v;
    }
    float x0 = X0[(size_t)(b * kT + t) * 8 + h];
    float scl = ssm_scale[0];
    const float* ow = Ow + ((size_t)h * 64 + d4 * 16) * 16;
    bf16* dst = Y + ((size_t)(b * kT + t)) * kDIM + 512 + h * 64 + d4 * 16;
    float yx = y * x0;
#pragma unroll
    for (int d = 0; d < 16; ++d) {
      float acc = yx;
      const float* owr = ow + d * 16;
#pragma unroll
      for (int s = 0; s < 16; ++s) acc += hv[s] * owr[s];
      dst[d] = __float2bfloat16(acc * scl);
    }
  }
}

// ---------------- host ----------------
extern "C" void kernel_launch(void* const* d_in, const int* in_sizes, int n_in,
                              void* d_out, int out_size, void* d_ws, size_t ws_size,
                              hipStream_t stream) {
  (void)in_sizes; (void)n_in; (void)out_size; (void)ws_size;
  const float* x        = (const float*)d_in[0];
  const float* meta     = (const float*)d_in[1];
  const float* c_q_w    = (const float*)d_in[2];
  const float* c_k_w    = (const float*)d_in[3];
  const float* c_v_w    = (const float*)d_in[4];
  const float* q_gain   = (const float*)d_in[5];
  const float* ssm_in_w = (const float*)d_in[6];
  const float* proj_w   = (const float*)d_in[7];
  const float* attn_sc  = (const float*)d_in[8];
  const float* ssm_sc   = (const float*)d_in[9];
  const float* ssm_logA = (const float*)d_in[10];
  const float* ssm_Bw   = (const float*)d_in[11];
  const float* ssm_Cw   = (const float*)d_in[12];
  const float* ssm_dtw  = (const float*)d_in[13];
  const float* ssm_dtb  = (const float*)d_in[14];
  const float* ssm_Ow   = (const float*)d_in[15];

  char* w = (char*)d_ws;
  bf16*  XE = (bf16*)(w + oXE);
  bf16*  YB = (bf16*)(w + oYB);
  bf16*  QP = (bf16*)(w + oQP);
  bf16*  KP = (bf16*)(w + oKP);
  bf16*  VT = (bf16*)(w + oVT);
  bf16*  WQ = (bf16*)(w + oWQ);
  bf16*  WP = (bf16*)(w + oWP);
  float* LU = (float*)(w + oLU);
  float* CC = (float*)(w + oCC);
  bf16*  HL = (bf16*)(w + oHL);
  float* X0 = (float*)(w + oX0);
  bf16*  AO = (bf16*)(w + oAO);
  float* AL = (float*)(w + oAL);

  prep_all<<<3632, 256, 0, stream>>>(c_q_w, c_k_w, c_v_w, ssm_in_w, proj_w,
                                     x, meta, WQ, WP, XE, QP, KP, VT);

  // QKV + SSM-prep fused GEMM
  gemm_t<0><<<dim3(24, kMPAD / 128), 256, 0, stream>>>(XE, WQ, QP, KP, VT, q_gain,
                                                       ssm_dtw, ssm_dtb, ssm_Bw, ssm_Cw,
                                                       ssm_logA, LU, CC, X0);

  // scan (blocks 0..63) + attention kv-split x3 (blocks 64..1647)
  attn_scan<<<64 + kQT * 3 * 8 * kB, 256, 0, stream>>>(QP, KP, VT, AO, AL, LU, HL);

  combine_out<<<1040, 256, 0, stream>>>(AO, AL, attn_sc, HL, CC, X0, ssm_Ow, ssm_sc, YB);

  gemm_t<2><<<dim3(16, kMX / 128), 256, 0, stream>>>(YB, WP, d_out, nullptr, nullptr, nullptr,
                                                     nullptr, nullptr, nullptr, nullptr, nullptr,
                                                     nullptr, nullptr, nullptr);
}

// Round 16
// 193.111 us; speedup vs baseline: 1.1749x; 1.0065x over previous
//
#include <hip/hip_runtime.h>
#include <hip/hip_bf16.h>
#include <math.h>

typedef __hip_bfloat16 bf16;
typedef __attribute__((ext_vector_type(8))) short short8;   // 8 bf16 = 4 VGPRs (MFMA A/B frag)
typedef __attribute__((ext_vector_type(4))) float f32x4;    // MFMA C/D frag

static constexpr int kB = 2;
static constexpr int kT = 2048;
static constexpr int kDIM = 1024;
static constexpr int kNMETA = 4;
static constexpr int kTEXT = kT + kNMETA;   // 2052
static constexpr int kMEXT = kB * kTEXT;    // 4104
static constexpr int kMPAD = 4224;          // 33*128
static constexpr int kMX = kB * kT;         // 4096
static constexpr int kQT = 33;
static constexpr int kTP = 2112;            // 33*64

// ---------- workspace layout (bytes); ws ~268 MB ----------
static constexpr size_t oXE = 0;                                  // x_ext bf16 [4224][1024]
static constexpr size_t oYB = 0;                                  // aliases XE (dead after GEMMs)
static constexpr size_t oLU = 8650752;                            // la/u interleaved f32x2 [4096][128]
static constexpr size_t oCC = oLU + (size_t)kMX * 128 * 8;        // Cc f32 [4096][128]
static constexpr size_t oHL = oCC + (size_t)kMX * 128 * 4;        // final h bf16 [4096][128]
static constexpr size_t oX0 = oHL + (size_t)kMX * 128 * 2;        // x0 f32 [4096][8]
static constexpr size_t oQP = oX0 + (size_t)kMX * 8 * 4;          // Qp bf16 [b][8][2112][64]
static constexpr size_t oKP = oQP + (size_t)kB * 8 * kTP * 64 * 2;// Kp bf16 [b][4][2112][64]
static constexpr size_t oVT = oKP + (size_t)kB * 4 * kTP * 64 * 2;// Vt bf16 [b][4][64][2112]
static constexpr size_t oWP = oVT + (size_t)kB * 4 * 64 * kTP * 2;// Wproj bf16 [1024][1024]
static constexpr size_t oWQ = oWP + (size_t)1024 * 1024 * 2;      // WQKV+WSX bf16 [1536][1024]
static constexpr size_t oAO = 134217728;                          // attn partial O bf16 [4][b][8][2112][64]
static constexpr size_t oAL = oAO + (size_t)4 * kB * 8 * kTP * 64 * 2;  // partial l f32 [4][b][8][2112]

#define GLD_LDS16(gp, lp)                                                          \
  __builtin_amdgcn_global_load_lds((const __attribute__((address_space(1))) void*)(gp), \
                                   (__attribute__((address_space(3))) void*)(lp), 16, 0, 0)

__device__ __forceinline__ short bf2s(float f) {
  union { bf16 h; short s; } u;
  u.h = __float2bfloat16(f);
  return u.s;
}

__device__ __forceinline__ float bf2f(unsigned short u) {
  return __uint_as_float(((unsigned int)u) << 16);
}

__device__ __forceinline__ uint4 pack8(float4 a, float4 b) {
  union { bf16 h[8]; uint4 v; } u;
  u.h[0] = __float2bfloat16(a.x); u.h[1] = __float2bfloat16(a.y);
  u.h[2] = __float2bfloat16(a.z); u.h[3] = __float2bfloat16(a.w);
  u.h[4] = __float2bfloat16(b.x); u.h[5] = __float2bfloat16(b.y);
  u.h[6] = __float2bfloat16(b.z); u.h[7] = __float2bfloat16(b.w);
  return u.v;
}

// accumulate 16 bf16 into f32[16]
__device__ __forceinline__ void add16bf(const bf16* p, float* o) {
  uint4 a = ((const uint4*)p)[0], b = ((const uint4*)p)[1];
  const unsigned short* s0 = (const unsigned short*)&a;
  const unsigned short* s1 = (const unsigned short*)&b;
#pragma unroll
  for (int i = 0; i < 8; ++i) { o[i] += bf2f(s0[i]); o[8 + i] += bf2f(s1[i]); }
}

// ---- prep: weight converts + x_ext build + QP/KP/VT tail zeroing, one launch ----
__global__ __launch_bounds__(256) void prep_all(const float* __restrict__ cq, const float* __restrict__ ck,
                                                const float* __restrict__ cv, const float* __restrict__ sw,
                                                const float* __restrict__ pw,
                                                const float* __restrict__ x, const float* __restrict__ meta,
                                                bf16* __restrict__ wqkvsx, bf16* __restrict__ wproj,
                                                bf16* __restrict__ xe,
                                                bf16* __restrict__ Qp, bf16* __restrict__ Kp,
                                                bf16* __restrict__ Vt) {
  int i = blockIdx.x * 256 + threadIdx.x;
  if (i < 327680) {                       // seg0: weights
    int row = i >> 7, v = i & 127;
    const float* src; bf16* dst;
    if (row < 512)       { src = cq + (size_t)row * 1024;          dst = wqkvsx + (size_t)row * 1024; }
    else if (row < 768)  { src = ck + (size_t)(row - 512) * 1024;  dst = wqkvsx + (size_t)row * 1024; }
    else if (row < 1024) { src = cv + (size_t)(row - 768) * 1024;  dst = wqkvsx + (size_t)row * 1024; }
    else if (row < 1536) { src = sw + (size_t)(row - 1024) * 1024; dst = wqkvsx + (size_t)row * 1024; }
    else                 { src = pw + (size_t)(row - 1536) * 1024; dst = wproj + (size_t)(row - 1536) * 1024; }
    float4 a0 = ((const float4*)src)[v * 2], a1 = ((const float4*)src)[v * 2 + 1];
    ((uint4*)dst)[v] = pack8(a0, a1);
  } else if (i < 868352) {                // seg1: x_ext
    int j = i - 327680;
    int r = j >> 7, v = j & 127;
    uint4 val = {0u, 0u, 0u, 0u};
    if (r < kMEXT) {
      int b = r / kTEXT, te = r - b * kTEXT;
      const float* src = (te < kNMETA) ? (meta + (size_t)te * kDIM)
                                       : (x + ((size_t)b * kT + (te - kNMETA)) * kDIM);
      float4 a0 = ((const float4*)src)[v * 2];
      float4 a1 = ((const float4*)src)[v * 2 + 1];
      val = pack8(a0, a1);
    }
    ((uint4*)(xe + (size_t)r * kDIM))[v] = val;
  } else {                                // seg2: zero pad tails (uint = 2 bf16)
    int j = i - 868352;
    if (j < 30720) {            // QP tails
      int k = j & 31, te = (j >> 5) % 60, bh = j / (60 * 32);
      *(unsigned int*)(Qp + ((size_t)bh * kTP + 2052 + te) * 64 + k * 2) = 0u;
    } else if (j < 46080) {     // KP tails
      int jj = j - 30720;
      int k = jj & 31, te = (jj >> 5) % 60, bh = jj / (60 * 32);
      *(unsigned int*)(Kp + ((size_t)bh * kTP + 2052 + te) * 64 + k * 2) = 0u;
    } else if (j < 61440) {     // VT tails
      int jj = j - 46080;
      int k = jj % 30, rowd = jj / 30;
      *(unsigned int*)(Vt + (size_t)rowd * kTP + 2052 + k * 2) = 0u;
    }
  }
}

// ========== 128x64-tile bf16 GEMM, BK=64 (2 panels), DOUBLE-BUFFERED GLD, 1 barrier/iter ====
template <int MODE>
__global__ __launch_bounds__(256) void gemm_t(const bf16* __restrict__ A,
                                              const bf16* __restrict__ W,
                                              void* __restrict__ O0, void* __restrict__ O1,
                                              void* __restrict__ O2,
                                              const float* __restrict__ q_gain,
                                              const float* __restrict__ dtw, const float* __restrict__ dtb,
                                              const float* __restrict__ Bw, const float* __restrict__ Cw,
                                              const float* __restrict__ logA,
                                              float* __restrict__ LU, float* __restrict__ CC,
                                              float* __restrict__ X0) {
  __shared__ char smem[49152];             // 2 x 24 KB; MODE0 epilogue overlay (25.3 KB) fits
  const int tid = threadIdx.x;
  const int wave = tid >> 6, lane = tid & 63;
  const int quad = lane >> 4, l16 = lane & 15;
  const int bm = blockIdx.y * 128, bn = blockIdx.x * 64;
  const bf16* ag0 = A + (size_t)(bm + (tid >> 2)) * 1024 + (tid & 3) * 8;        // rows 0..63
  const bf16* ag1 = A + (size_t)(bm + 64 + (tid >> 2)) * 1024 + (tid & 3) * 8;   // rows 64..127
  const bf16* bg0 = W + (size_t)(bn + (tid >> 2)) * 1024 + (tid & 3) * 8;
  f32x4 acc[2][4] = {};
  {  // prefetch iter 0 into buf0
    char* sb = smem + wave * 1024;
    GLD_LDS16(ag0, sb);
    GLD_LDS16(ag1, sb + 4096);
    GLD_LDS16(ag0 + 32, sb + 8192);
    GLD_LDS16(ag1 + 32, sb + 12288);
    GLD_LDS16(bg0, sb + 16384);
    GLD_LDS16(bg0 + 32, sb + 20480);
    ag0 += 64; ag1 += 64; bg0 += 64;
  }
  for (int k = 0; k < 16; ++k) {
    char* cur = smem + (k & 1) * 24576;
    char* nxt = smem + ((k & 1) ^ 1) * 24576;
    __syncthreads();                       // cur's loads landed (in flight a full iter)
    if (k < 15) {                          // issue next tile into the other buffer
      char* sb = nxt + wave * 1024;
      GLD_LDS16(ag0, sb);
      GLD_LDS16(ag1, sb + 4096);
      GLD_LDS16(ag0 + 32, sb + 8192);
      GLD_LDS16(ag1 + 32, sb + 12288);
      GLD_LDS16(bg0, sb + 16384);
      GLD_LDS16(bg0 + 32, sb + 20480);
      ag0 += 64; ag1 += 64; bg0 += 64;
    }
#pragma unroll
    for (int p = 0; p < 2; ++p) {
      short8 af[2], bfr[4];
#pragma unroll
      for (int mi = 0; mi < 2; ++mi)
        af[mi] = *(const short8*)(cur + p * 8192 +
                                  (size_t)(wave * 32 + mi * 16 + l16) * 64 + quad * 16);
#pragma unroll
      for (int ni = 0; ni < 4; ++ni)
        bfr[ni] = *(const short8*)(cur + 16384 + p * 4096 +
                                   (size_t)(ni * 16 + l16) * 64 + quad * 16);
#pragma unroll
      for (int mi = 0; mi < 2; ++mi)
#pragma unroll
        for (int ni = 0; ni < 4; ++ni)
          acc[mi][ni] = __builtin_amdgcn_mfma_f32_16x16x32_bf16(af[mi], bfr[ni], acc[mi][ni], 0, 0, 0);
    }
  }
  // ---- epilogue ----
  if constexpr (MODE == 2) {
#pragma unroll
    for (int mi = 0; mi < 2; ++mi)
#pragma unroll
      for (int ni = 0; ni < 4; ++ni) {
        int colg = bn + ni * 16 + l16;
#pragma unroll
        for (int r = 0; r < 4; ++r) {
          int row = bm + wave * 32 + mi * 16 + quad * 4 + r;
          ((float*)O0)[(size_t)row * 1024 + colg] = acc[mi][ni][r];
        }
      }
  } else {
    const int tile = blockIdx.x;
    if (tile < 16) {
      float gain = (tile < 8) ? q_gain[tile] * 0.125f : 1.f;
      float inv0 = exp2f(-13.287712379549449f * (float)l16 * (1.f / 32.f));
      float inv1 = exp2f(-13.287712379549449f * (float)(l16 + 16) * (1.f / 32.f));
#pragma unroll
      for (int mi = 0; mi < 2; ++mi) {
        int row0 = bm + wave * 32 + mi * 16 + quad * 4;
        if (row0 >= kMEXT) continue;          // 4-row group fully pad
        int b = row0 >= kTEXT ? 1 : 0;
        int te0 = row0 - b * kTEXT;
        if (tile < 12) {
          float ss[4];
#pragma unroll
          for (int r = 0; r < 4; ++r) {
            float s = 0.f;
#pragma unroll
            for (int ni = 0; ni < 4; ++ni) s += acc[mi][ni][r] * acc[mi][ni][r];
#pragma unroll
            for (int off = 1; off < 16; off <<= 1) s += __shfl_xor(s, off, 64);
            ss[r] = s;
          }
          bf16* base = (tile < 8)
            ? (bf16*)O0 + (((size_t)(b * 8 + tile)) * kTP + te0) * 64 + l16
            : (bf16*)O1 + (((size_t)(b * 4 + tile - 8)) * kTP + te0) * 64 + l16;
#pragma unroll
          for (int r = 0; r < 4; ++r) {
            float rn = rsqrtf(ss[r] * (1.f / 64.f) + 1e-6f) * gain;
            float te = (float)(te0 + r);
            float a0 = te * inv0, a1 = te * inv1;
            float c0 = __cosf(a0), s0 = __sinf(a0);
            float c1 = __cosf(a1), s1 = __sinf(a1);
            float v0 = acc[mi][0][r] * rn, v1 = acc[mi][1][r] * rn;
            float v2 = acc[mi][2][r] * rn, v3 = acc[mi][3][r] * rn;
            bf16* dst = base + (size_t)r * 64;
            dst[0]  = __float2bfloat16(v0 * c0 - v2 * s0);
            dst[16] = __float2bfloat16(v1 * c1 - v3 * s1);
            dst[32] = __float2bfloat16(v0 * s0 + v2 * c0);
            dst[48] = __float2bfloat16(v1 * s1 + v3 * c1);
          }
        } else {
          int hv = tile - 12;
#pragma unroll
          for (int ni = 0; ni < 4; ++ni) {
            union { unsigned long long q; bf16 hh[4]; } pw;
#pragma unroll
            for (int r = 0; r < 4; ++r) pw.hh[r] = __float2bfloat16(acc[mi][ni][r]);
            *(unsigned long long*)((bf16*)O2 +
                (((size_t)(b * 4 + hv)) * 64 + ni * 16 + l16) * kTP + te0) = pw.q;
          }
        }
      }
    } else {
      // ---- fused SSM prep: X (in acc) vs [dtw;Bw;Cw] of head hd ----
      const int hd = tile - 16;
      __syncthreads();   // all GEMM LDS reads done; smem reusable
      short (*Xl)[72] = (short(*)[72])smem;
      short (*Wl)[72] = (short(*)[72])(smem + 18432);
#pragma unroll
      for (int mi = 0; mi < 2; ++mi) {
        if (l16 == 0) {
#pragma unroll
          for (int r = 0; r < 4; ++r) {
            int row = bm + wave * 32 + mi * 16 + quad * 4 + r;
            if (row < kMEXT) {
              int bb = row >= kTEXT ? 1 : 0;
              int te = row - bb * kTEXT;
              if (te >= kNMETA) X0[(size_t)(bb * kT + te - kNMETA) * 8 + hd] = acc[mi][0][r];
            }
          }
        }
      }
#pragma unroll
      for (int mi = 0; mi < 2; ++mi)
#pragma unroll
        for (int ni = 0; ni < 4; ++ni)
#pragma unroll
          for (int r = 0; r < 4; ++r)
            Xl[wave * 32 + mi * 16 + quad * 4 + r][ni * 16 + l16] = bf2s(acc[mi][ni][r]);
      for (int s2 = tid; s2 < 384; s2 += 256) {
        int row = s2 >> 3, v = s2 & 7;
        const float* src = (row < 16) ? dtw + ((size_t)(hd * 16 + row)) * 64
                         : (row < 32) ? Bw + ((size_t)(hd * 16 + row - 16)) * 64
                                      : Cw + ((size_t)(hd * 16 + row - 32)) * 64;
        float4 a0 = ((const float4*)src)[v * 2];
        float4 a1 = ((const float4*)src)[v * 2 + 1];
        *(uint4*)&Wl[row][v * 8] = pack8(a0, a1);
      }
      __syncthreads();
      f32x4 a3[2][3] = {};
#pragma unroll
      for (int mt = 0; mt < 2; ++mt) {
        short8 xa0 = *(const short8*)&Xl[wave * 32 + mt * 16 + l16][quad * 8];
        short8 xa1 = *(const short8*)&Xl[wave * 32 + mt * 16 + l16][32 + quad * 8];
#pragma unroll
        for (int nb = 0; nb < 3; ++nb) {
          short8 wb0 = *(const short8*)&Wl[nb * 16 + l16][quad * 8];
          a3[mt][nb] = __builtin_amdgcn_mfma_f32_16x16x32_bf16(xa0, wb0, a3[mt][nb], 0, 0, 0);
          short8 wb1 = *(const short8*)&Wl[nb * 16 + l16][32 + quad * 8];
          a3[mt][nb] = __builtin_amdgcn_mfma_f32_16x16x32_bf16(xa1, wb1, a3[mt][nb], 0, 0, 0);
        }
      }
      float dtb_v = dtb[hd * 16 + l16];
      float A_v = fminf(-expf(logA[hd * 16 + l16]), 10.f);
#pragma unroll
      for (int mt = 0; mt < 2; ++mt)
#pragma unroll
        for (int r = 0; r < 4; ++r) {
          int row = bm + wave * 32 + mt * 16 + quad * 4 + r;
          if (row >= kMEXT) continue;
          int bb = row >= kTEXT ? 1 : 0;
          int te = row - bb * kTEXT;
          if (te < kNMETA) continue;
          size_t ix = (size_t)(bb * kT + te - kNMETA) * 128 + hd * 16 + l16;
          float raw = a3[mt][0][r] + dtb_v;
          float sp = fmaxf(raw, 0.f) + log1pf(expf(-fabsf(raw)));   // stable softplus
          float dt = fminf(sp, 1.f);
          float lav = fminf(fmaxf(dt * A_v, -0.5f), 0.f);
          *(float2*)(LU + 2 * ix) = make_float2(lav, a3[mt][1][r] * dt);
          CC[ix] = a3[mt][2][r];
        }
    }
  }
}

// ===== fused: SSM scan (blocks 0..63) + MFMA attention, 2 heads/block, kv-split x4 =====
__global__ __launch_bounds__(256) void attn_scan(const bf16* __restrict__ Qp,
                                                 const bf16* __restrict__ Kp,
                                                 const bf16* __restrict__ Vt,
                                                 bf16* __restrict__ AO, float* __restrict__ AL,
                                                 const float* __restrict__ LU, bf16* __restrict__ HL) {
  __shared__ char sraw[27648];
  if (blockIdx.x < 64) {
    float (*sH)[64] = (float(*)[64])sraw;
    float (*sP)[64] = (float(*)[64])(sraw + 1024);
    float (*sH0)[64] = (float(*)[64])(sraw + 2048);
    const int tid = threadIdx.x;
    const int ch = tid & 3, c = tid >> 2;
    const int chain = blockIdx.x * 4 + ch;       // 0..255
    const int b = chain >> 7, hs = chain & 127;
    const float2* LU2 = (const float2*)LU;
    const size_t base = ((size_t)b * kT) * 128 + hs;
    float H = 0.f, cum = 0.f;
    for (int i = 0; i < 32; ++i) {
      float2 lu = LU2[base + (size_t)(c * 32 + i) * 128];
      cum += lu.x;
      H = __expf(lu.x) * H + lu.y;
    }
    sH[ch][c] = H;
    sP[ch][c] = __expf(cum);       // cum >= -16, no clip needed
    __syncthreads();
    const int wv = tid >> 6, lane = tid & 63;
    float Hs = sH[wv][lane], Ps = sP[wv][lane];
#pragma unroll
    for (int off = 1; off < 64; off <<= 1) {
      float Hp = __shfl_up(Hs, off, 64);
      float Pp = __shfl_up(Ps, off, 64);
      if (lane >= off) { Hs = Hs + Ps * Hp; Ps = Ps * Pp; }
    }
    float Hex = __shfl_up(Hs, 1, 64);
    if (lane == 0) Hex = 0.f;
    sH0[wv][lane] = Hex;
    __syncthreads();
    float h = sH0[ch][c];          // exclusive prefix = h entering this sub-chunk
    for (int i = 0; i < 32; ++i) {
      size_t ix = base + (size_t)(c * 32 + i) * 128;
      float2 lu = LU2[ix];
      h = __expf(lu.x) * h + lu.y;
      HL[ix] = __float2bfloat16(h);
    }
    return;
  }
  // ---------- attention: 2 heads per block (shared K/V), kv-split x4 ----------
  short (*Ks)[72] = (short(*)[72])sraw;
  short (*Vs)[72] = (short(*)[72])(sraw + 9216);
  short (*Ps)[16][72] = (short(*)[16][72])(sraw + 18432);
  const int i = blockIdx.x - 64;              // 0..1055 : xq = i%132, kvh = (i/132)%4, b = i/528
  const int xq = i % 132;
  const int kvh = (i / 132) & 3, b = i / 528;
  const int part = xq & 3;
  const int qt = (kQT - 1) - (xq >> 2);       // longest first
  const int h0 = kvh * 2;
  const int tid = threadIdx.x, wave = tid >> 6, lane = tid & 63;
  const int quad = lane >> 4, l16 = lane & 15;
  const int ntiles = qt + 1;
  const int kt_begin = (part * ntiles) >> 2;
  const int kt_end = ((part + 1) * ntiles) >> 2;   // exclusive
  if (kt_begin >= kt_end) return;             // empty split: combine skips this part

  short8 qf[2][2];
#pragma unroll
  for (int hh = 0; hh < 2; ++hh) {
    const bf16* qrow = Qp + (((size_t)(b * 8 + h0 + hh)) * kTP + qt * 64 + wave * 16 + l16) * 64 + quad * 8;
    qf[hh][0] = *(const short8*)(qrow);
    qf[hh][1] = *(const short8*)(qrow + 32);
  }
  short8 ones;
#pragma unroll
  for (int j = 0; j < 8; ++j) ones[j] = (short)0x3F80;   // bf16 1.0

  const bf16* kbase = Kp + ((size_t)(b * 4 + kvh)) * kTP * 64;
  const bf16* vbase = Vt + ((size_t)(b * 4 + kvh)) * 64 * kTP;

  const int r0row = tid >> 3, r0c8 = tid & 7;
  const int r1row = (256 + tid) >> 3, r1c8 = tid & 7;

  f32x4 O[2][4] = {};
  f32x4 lacc[2] = {};
  const int q_abs = qt * 64 + wave * 16 + l16;

  uint4 kr0 = *(const uint4*)(kbase + (size_t)(kt_begin * 64 + r0row) * 64 + r0c8 * 8);
  uint4 kr1 = *(const uint4*)(kbase + (size_t)(kt_begin * 64 + r1row) * 64 + r1c8 * 8);
  uint4 vr0 = *(const uint4*)(vbase + (size_t)r0row * kTP + kt_begin * 64 + r0c8 * 8);
  uint4 vr1 = *(const uint4*)(vbase + (size_t)r1row * kTP + kt_begin * 64 + r1c8 * 8);

  for (int kt = kt_begin; kt < kt_end; ++kt) {
    __syncthreads();
    *(uint4*)&Ks[r0row][r0c8 * 8] = kr0;
    *(uint4*)&Ks[r1row][r1c8 * 8] = kr1;
    *(uint4*)&Vs[r0row][r0c8 * 8] = vr0;
    *(uint4*)&Vs[r1row][r1c8 * 8] = vr1;
    if (kt + 1 < kt_end) {
      int kn = (kt + 1) * 64;
      kr0 = *(const uint4*)(kbase + (size_t)(kn + r0row) * 64 + r0c8 * 8);
      kr1 = *(const uint4*)(kbase + (size_t)(kn + r1row) * 64 + r1c8 * 8);
      vr0 = *(const uint4*)(vbase + (size_t)r0row * kTP + kn + r0c8 * 8);
      vr1 = *(const uint4*)(vbase + (size_t)r1row * kTP + kn + r1c8 * 8);
    }
    __syncthreads();

    // ---- S^T = K * Q^T for both heads; K-fragments read once ----
    f32x4 st[2][4] = {};
#pragma unroll
    for (int nb = 0; nb < 4; ++nb) {
      short8 ak0 = *(const short8*)&Ks[nb * 16 + l16][quad * 8];
      short8 ak1 = *(const short8*)&Ks[nb * 16 + l16][32 + quad * 8];
#pragma unroll
      for (int hh = 0; hh < 2; ++hh) {
        st[hh][nb] = __builtin_amdgcn_mfma_f32_16x16x32_bf16(ak0, qf[hh][0], st[hh][nb], 0, 0, 0);
        st[hh][nb] = __builtin_amdgcn_mfma_f32_16x16x32_bf16(ak1, qf[hh][1], st[hh][nb], 0, 0, 0);
      }
    }
    if (kt == qt) {
      int key0 = kt * 64 + quad * 4;
#pragma unroll
      for (int nb = 0; nb < 4; ++nb)
#pragma unroll
        for (int rg = 0; rg < 4; ++rg)
          if (key0 + nb * 16 + rg > q_abs) { st[0][nb][rg] = -1e30f; st[1][nb][rg] = -1e30f; }
    }
    // ---- per-head P round-trip (wave-private LDS, in-wave DS ordering) ----
    short8 pf[2][2];
#pragma unroll
    for (int hh = 0; hh < 2; ++hh) {
#pragma unroll
      for (int nb = 0; nb < 4; ++nb) {
        union { unsigned long long q; bf16 hv4[4]; } pw;
#pragma unroll
        for (int rg = 0; rg < 4; ++rg) pw.hv4[rg] = __float2bfloat16(__expf(st[hh][nb][rg]));
        *(unsigned long long*)&Ps[wave][l16][nb * 16 + quad * 4] = pw.q;
      }
      pf[hh][0] = *(const short8*)&Ps[wave][l16][quad * 8];
      pf[hh][1] = *(const short8*)&Ps[wave][l16][32 + quad * 8];
      lacc[hh] = __builtin_amdgcn_mfma_f32_16x16x32_bf16(pf[hh][0], ones, lacc[hh], 0, 0, 0);
      lacc[hh] = __builtin_amdgcn_mfma_f32_16x16x32_bf16(pf[hh][1], ones, lacc[hh], 0, 0, 0);
    }
    // ---- O += P @ V; V-fragments read once for both heads ----
#pragma unroll
    for (int db = 0; db < 4; ++db) {
      short8 bv0 = *(const short8*)&Vs[db * 16 + l16][quad * 8];
      short8 bv1 = *(const short8*)&Vs[db * 16 + l16][32 + quad * 8];
#pragma unroll
      for (int hh = 0; hh < 2; ++hh) {
        O[hh][db] = __builtin_amdgcn_mfma_f32_16x16x32_bf16(pf[hh][0], bv0, O[hh][db], 0, 0, 0);
        O[hh][db] = __builtin_amdgcn_mfma_f32_16x16x32_bf16(pf[hh][1], bv1, O[hh][db], 0, 0, 0);
      }
    }
  }
#pragma unroll
  for (int hh = 0; hh < 2; ++hh) {
    size_t hb = (((size_t)part * 2 + b) * 8 + h0 + hh);
    bf16* aoB = AO + hb * kTP * 64;
    float* alB = AL + hb * kTP;
#pragma unroll
    for (int rg = 0; rg < 4; ++rg) {
      int q = qt * 64 + wave * 16 + quad * 4 + rg;
      bf16* dst = aoB + (size_t)q * 64 + l16;
#pragma unroll
      for (int db = 0; db < 4; ++db) dst[db * 16] = __float2bfloat16(O[hh][db][rg]);
      if (l16 == 0) alB[q] = lacc[hh][rg];
    }
  }
}

// ------- fused: attn kv-split x4 combine (blocks 0..527) + ssm output (blocks 528..1039) -------
__global__ __launch_bounds__(256) void combine_out(const bf16* __restrict__ AO,
                                                   const float* __restrict__ AL,
                                                   const float* __restrict__ attn_scale,
                                                   const bf16* __restrict__ HL, const float* __restrict__ CC,
                                                   const float* __restrict__ X0, const float* __restrict__ Ow,
                                                   const float* __restrict__ ssm_scale,
                                                   bf16* __restrict__ Y) {
  if (blockIdx.x < 528) {
    int id = blockIdx.x * 256 + threadIdx.x;     // 2*8*2112*4
    int d16 = id & 3;
    int tmp = id >> 2;
    int q = tmp % kTP; tmp /= kTP;
    int h = tmp & 7, b = tmp >> 3;
    if (q < kNMETA || q >= kTEXT) return;
    int ntiles = (q >> 6) + 1;
    float l = 0.f;
    float ov[16];
#pragma unroll
    for (int j = 0; j < 16; ++j) ov[j] = 0.f;
#pragma unroll
    for (int p = 0; p < 4; ++p) {
      if (((p * ntiles) >> 2) < (((p + 1) * ntiles) >> 2)) {   // part active
        size_t hb = (((size_t)p * 2 + b) * 8 + h);
        l += AL[hb * kTP + q];
        add16bf(AO + (hb * kTP + q) * 64 + d16 * 16, ov);
      }
    }
    float so = attn_scale[0] / fmaxf(l, 1e-30f);
    bf16* dst = Y + ((size_t)(b * kT + q - kNMETA)) * kDIM + h * 64 + d16 * 16;
#pragma unroll
    for (int j = 0; j < 16; ++j) dst[j] = __float2bfloat16(ov[j] * so);
  } else {
    int id = (blockIdx.x - 528) * 256 + threadIdx.x;   // kMX*32
    int d4 = id & 3, h = (id >> 2) & 7, t = (id >> 5) & 2047, b = id >> 16;
    size_t ix0 = ((size_t)(b * kT + t)) * 128 + h * 16;
    float hv[16], y = 0.f;
#pragma unroll
    for (int s = 0; s < 16; ++s) {
      float v = __bfloat162float(HL[ix0 + s]);
      hv[s] = v;
      y += CC[ix0 + s] * v;
    }
    float x0 = X0[(size_t)(b * kT + t) * 8 + h];
    float scl = ssm_scale[0];
    const float* ow = Ow + ((size_t)h * 64 + d4 * 16) * 16;
    bf16* dst = Y + ((size_t)(b * kT + t)) * kDIM + 512 + h * 64 + d4 * 16;
    float yx = y * x0;
#pragma unroll
    for (int d = 0; d < 16; ++d) {
      float acc = yx;
      const float* owr = ow + d * 16;
#pragma unroll
      for (int s = 0; s < 16; ++s) acc += hv[s] * owr[s];
      dst[d] = __float2bfloat16(acc * scl);
    }
  }
}

// ---------------- host ----------------
extern "C" void kernel_launch(void* const* d_in, const int* in_sizes, int n_in,
                              void* d_out, int out_size, void* d_ws, size_t ws_size,
                              hipStream_t stream) {
  (void)in_sizes; (void)n_in; (void)out_size; (void)ws_size;
  const float* x        = (const float*)d_in[0];
  const float* meta     = (const float*)d_in[1];
  const float* c_q_w    = (const float*)d_in[2];
  const float* c_k_w    = (const float*)d_in[3];
  const float* c_v_w    = (const float*)d_in[4];
  const float* q_gain   = (const float*)d_in[5];
  const float* ssm_in_w = (const float*)d_in[6];
  const float* proj_w   = (const float*)d_in[7];
  const float* attn_sc  = (const float*)d_in[8];
  const float* ssm_sc   = (const float*)d_in[9];
  const float* ssm_logA = (const float*)d_in[10];
  const float* ssm_Bw   = (const float*)d_in[11];
  const float* ssm_Cw   = (const float*)d_in[12];
  const float* ssm_dtw  = (const float*)d_in[13];
  const float* ssm_dtb  = (const float*)d_in[14];
  const float* ssm_Ow   = (const float*)d_in[15];

  char* w = (char*)d_ws;
  bf16*  XE = (bf16*)(w + oXE);
  bf16*  YB = (bf16*)(w + oYB);
  bf16*  QP = (bf16*)(w + oQP);
  bf16*  KP = (bf16*)(w + oKP);
  bf16*  VT = (bf16*)(w + oVT);
  bf16*  WQ = (bf16*)(w + oWQ);
  bf16*  WP = (bf16*)(w + oWP);
  float* LU = (float*)(w + oLU);
  float* CC = (float*)(w + oCC);
  bf16*  HL = (bf16*)(w + oHL);
  float* X0 = (float*)(w + oX0);
  bf16*  AO = (bf16*)(w + oAO);
  float* AL = (float*)(w + oAL);

  prep_all<<<3632, 256, 0, stream>>>(c_q_w, c_k_w, c_v_w, ssm_in_w, proj_w,
                                     x, meta, WQ, WP, XE, QP, KP, VT);

  // QKV + SSM-prep fused GEMM
  gemm_t<0><<<dim3(24, kMPAD / 128), 256, 0, stream>>>(XE, WQ, QP, KP, VT, q_gain,
                                                       ssm_dtw, ssm_dtb, ssm_Bw, ssm_Cw,
                                                       ssm_logA, LU, CC, X0);

  // scan (blocks 0..63) + attention 2-heads/block kv-split x4 (blocks 64..1119)
  attn_scan<<<64 + kQT * 4 * 4 * kB, 256, 0, stream>>>(QP, KP, VT, AO, AL, LU, HL);

  combine_out<<<1040, 256, 0, stream>>>(AO, AL, attn_sc, HL, CC, X0, ssm_Ow, ssm_sc, YB);

  gemm_t<2><<<dim3(16, kMX / 128), 256, 0, stream>>>(YB, WP, d_out, nullptr, nullptr, nullptr,
                                                     nullptr, nullptr, nullptr, nullptr, nullptr,
                                                     nullptr, nullptr, nullptr);
}